// Round 14
// baseline (350.598 us; speedup 1.0000x reference)
//
#include <hip/hip_runtime.h>
#include <hip/hip_bf16.h>

#define SEQ 2048
#define HIDDEN 4096
#define NH 32
#define NKV 8
#define HD 128
#define QKV_OUT 6144   // (32 + 2*8) * 128
// Q is pre-scaled by SM_SCALE*log2(e) so softmax uses exp2 directly.
#define QSCALE (0.0078125f * 1.4426950408889634f)

typedef __attribute__((ext_vector_type(8))) short bf16x8;
typedef __attribute__((ext_vector_type(4))) float f32x4;
typedef __attribute__((ext_vector_type(16))) float f32x16;

__device__ inline unsigned short f32_bf16(float f) {
  union { float f; unsigned int u; } v; v.f = f;
  unsigned int r = v.u + 0x7FFFu + ((v.u >> 16) & 1u);
  return (unsigned short)(r >> 16);
}
__device__ inline float bf16_f32(unsigned short u) {
  union { unsigned int u; float f; } v; v.u = (unsigned int)u << 16;
  return v.f;
}
__device__ inline unsigned int pk(float a, float b) {
  union { __hip_bfloat162 h; unsigned int u; } t;
  t.h = __float22bfloat162_rn(make_float2(a, b));
  return t.u;
}
__device__ inline void pswap(unsigned int &a, unsigned int &b) {
  auto r = __builtin_amdgcn_permlane32_swap((int)a, (int)b, false, false);
  a = (unsigned int)r[0]; b = (unsigned int)r[1];
}
__device__ inline float xmax32(float v) {
  int x = __builtin_bit_cast(int, v);
  auto r = __builtin_amdgcn_permlane32_swap(x, x, false, false);
  return fmaxf(__builtin_bit_cast(float, (int)r[0]), __builtin_bit_cast(float, (int)r[1]));
}
__device__ inline float xadd32(float v) {
  int x = __builtin_bit_cast(int, v);
  auto r = __builtin_amdgcn_permlane32_swap(x, x, false, false);
  return __builtin_bit_cast(float, (int)r[0]) + __builtin_bit_cast(float, (int)r[1]);
}

// ---------------- fp32 -> bf16 bulk conversion (hidden states only) ----------
__global__ __launch_bounds__(256) void conv_bf16(const float* __restrict__ in,
                                                 unsigned short* __restrict__ out,
                                                 int n) {
  int i = (blockIdx.x * 256 + threadIdx.x) * 8;
  if (i + 8 > n) return;
  float4 a = *reinterpret_cast<const float4*>(in + i);
  float4 b = *reinterpret_cast<const float4*>(in + i + 4);
  unsigned short t[8];
  t[0] = f32_bf16(a.x); t[1] = f32_bf16(a.y); t[2] = f32_bf16(a.z); t[3] = f32_bf16(a.w);
  t[4] = f32_bf16(b.x); t[5] = f32_bf16(b.y); t[6] = f32_bf16(b.z); t[7] = f32_bf16(b.w);
  *reinterpret_cast<uint4*>(out + i) = *reinterpret_cast<uint4*>(t);
}

// ---------------- RoPE cos/sin tables [SEQ][64] ----------------
__global__ __launch_bounds__(256) void build_tab(float* __restrict__ ct,
                                                 float* __restrict__ st) {
  int idx = blockIdx.x * 256 + threadIdx.x;  // SEQ*64
  int s = idx >> 6, d = idx & 63;
  float inv = powf(1.0e6f, -(float)d * (1.0f / 64.0f));
  float f = (float)s * inv;
  ct[idx] = cosf(f);
  st[idx] = sinf(f);
}

// ---------------- fused-cast GEMM: C = A_bf16 * B_fp32^T + bias --------------
// BM=128, BN=256, BK=64. 512 threads = 8 waves (2M x 4N). R11 gemm9's proven
// LDS layout / zero-conflict swizzle (chunk ^= row&7) / phase bodies, with the
// B operand read as FP32 from global and cast in-kernel:
//   depth-2 reg pipeline: load B(t+2) fp32 at tile t -> vmcnt(10) (B(t+1) regs
//   + A(t) DMA are >=1 full tile old) -> barrier -> cvt_pk + ds_write_b128 of
//   B(t+1) into the other buffer (unread until barrier t+1; disjoint from the
//   A-DMA section; lgkm0 before each barrier publishes the writes).
// Even/odd loop unroll keeps the B reg arrays statically indexed.
template <int CR, int CC, bool OBF>
__global__ __launch_bounds__(512, 2) void gemmW(const unsigned short* __restrict__ A,
                                                const float* __restrict__ B,
                                                const float* __restrict__ bias,
                                                void* __restrict__ Cp,
                                                int M, int N, int K) {
  constexpr int BM = 128, BN = 256;
  constexpr int MQ = BM / 64;          // A frags per quadrant = 2
  constexpr int ABYT = BM * 128;       // 16 KB A section per buffer
  constexpr int SB = ABYT + 32768;     // 48 KB per buffer
  constexpr int NA = BM / 64;          // A gloads per wave per tile = 2
  __shared__ __align__(16) char Lds[SB * 2];

  const int tid = threadIdx.x;
  const int wave = tid >> 6, lane = tid & 63;
  const int wr = wave >> 2, wc = wave & 3;
  const int lrow = lane & 15, lgrp = lane >> 4;

  // 2D XCD chunk
  const int ntx = N / BN;
  const int wg0 = blockIdx.x;
  const int xcd = wg0 & 7, w = wg0 >> 3;
  const int cpb = ntx / CC;
  const int band = xcd / cpb, colc = xcd % cpb;
  const int bm = (band * CR + w / CC) * BM;
  const int bn = (colc * CC + w % CC) * BN;

  const int r8 = lane >> 3, c8 = lane & 7;
  // A staging: global_load_lds, pre-swizzled source chunk ^ r8 (bf16)
  const int scolA = (c8 ^ r8) * 8;
  const unsigned short* gA[NA]; int lA[NA];
#pragma unroll
  for (int j = 0; j < NA; ++j) {
    int row = bm + wave * (BM / 8) + j * 8 + r8;
    gA[j] = A + (size_t)row * K + scolA;
    lA[j] = wave * (BM / 8) * 128 + j * 1024;
  }
  auto stageA = [&](int t) {
    const int bufb = (t & 1) * SB;
#pragma unroll
    for (int j = 0; j < NA; ++j)
      __builtin_amdgcn_global_load_lds(
          (const __attribute__((address_space(1))) unsigned int*)(gA[j] + t * 64),
          (__attribute__((address_space(3))) unsigned int*)(Lds + bufb + lA[j]), 16, 0, 0);
  };

  // B: fp32 source, same swizzle in 16B-bf16-chunk units (source chunk c8^r8
  // covers k = s*8..s*8+7 -> fp32 elem offset s*8, two 16B loads)
  const float* gBs[4]; int lB[4];
#pragma unroll
  for (int j = 0; j < 4; ++j) {
    int row = bn + wave * 32 + j * 8 + r8;
    gBs[j] = B + (size_t)row * K + (c8 ^ r8) * 8;
    lB[j] = ABYT + (wave * 32 + j * 8 + r8) * 128 + c8 * 16;  // linear dest chunk
  }
  auto loadB = [&](f32x4 (&dst)[4][2], int t) {
#pragma unroll
    for (int j = 0; j < 4; ++j) {
      dst[j][0] = *reinterpret_cast<const f32x4*>(gBs[j] + t * 64);
      dst[j][1] = *reinterpret_cast<const f32x4*>(gBs[j] + t * 64 + 4);
    }
  };
  auto writeB = [&](f32x4 (&src)[4][2], int t) {  // into buffer (t&1)
    char* bb = Lds + (t & 1) * SB;
#pragma unroll
    for (int j = 0; j < 4; ++j) {
      uint4 u;
      u.x = pk(src[j][0][0], src[j][0][1]);
      u.y = pk(src[j][0][2], src[j][0][3]);
      u.z = pk(src[j][1][0], src[j][1][1]);
      u.w = pk(src[j][1][2], src[j][1][3]);
      *reinterpret_cast<uint4*>(bb + lB[j]) = u;
    }
  };

  // fragment read offsets (R11 gemm9, unchanged)
  const int rsw = (lrow & 7) << 4;
  auto aoff = [&](int mh, int m, int ks) {
    return (wr * (BM / 2) + mh * (BM / 4) + m * 16 + lrow) * 128 +
           ((ks * 64 + lgrp * 16) ^ rsw);
  };
  auto boff = [&](int nh, int n, int ks) {
    return ABYT + (wc * 64 + nh * 32 + n * 16 + lrow) * 128 +
           ((ks * 64 + lgrp * 16) ^ rsw);
  };

  f32x4 acc[2 * MQ][4] = {};
  bf16x8 af[MQ][2], bf0[2][2], bf1[2][2];
  f32x4 bE[4][2], bO[4][2];
  const int nt = K / 64;

  // prologue: B(0)->bE, A(0); drain them (leave B(1) in flight); write B(0).
  loadB(bE, 0);
  stageA(0);
  loadB(bO, 1);
  asm volatile("s_waitcnt vmcnt(8)" ::: "memory");
  __builtin_amdgcn_sched_barrier(0);
  writeB(bE, 0);
  asm volatile("s_waitcnt lgkmcnt(0)" ::: "memory");
  __builtin_amdgcn_sched_barrier(0);

  auto tileStep = [&](int t, f32x4 (&wsrc)[4][2], f32x4 (&ldst)[4][2]) {
    const bool pf1 = (t + 1) < nt, pf2 = (t + 2) < nt;
    if (pf2) loadB(ldst, t + 2);
    if (pf1) stageA(t + 1);
    if (pf2)      asm volatile("s_waitcnt vmcnt(10) lgkmcnt(0)" ::: "memory");
    else if (pf1) asm volatile("s_waitcnt vmcnt(2) lgkmcnt(0)" ::: "memory");
    else          asm volatile("s_waitcnt vmcnt(0) lgkmcnt(0)" ::: "memory");
    __builtin_amdgcn_sched_barrier(0);
    __builtin_amdgcn_s_barrier();
    __builtin_amdgcn_sched_barrier(0);
    if (pf1) writeB(wsrc, t + 1);  // other buffer: unread until next barrier

    const char* base = Lds + (t & 1) * SB;
    // q0
#pragma unroll
    for (int m = 0; m < MQ; ++m)
#pragma unroll
      for (int ks = 0; ks < 2; ++ks)
        af[m][ks] = *reinterpret_cast<const bf16x8*>(base + aoff(0, m, ks));
#pragma unroll
    for (int n = 0; n < 2; ++n)
#pragma unroll
      for (int ks = 0; ks < 2; ++ks)
        bf0[n][ks] = *reinterpret_cast<const bf16x8*>(base + boff(0, n, ks));
    __builtin_amdgcn_s_setprio(1);
#pragma unroll
    for (int m = 0; m < MQ; ++m)
#pragma unroll
      for (int n = 0; n < 2; ++n)
#pragma unroll
        for (int ks = 0; ks < 2; ++ks)
          acc[m][n] = __builtin_amdgcn_mfma_f32_16x16x32_bf16(af[m][ks], bf0[n][ks], acc[m][n], 0, 0, 0);
    __builtin_amdgcn_s_setprio(0);
    // q1
#pragma unroll
    for (int n = 0; n < 2; ++n)
#pragma unroll
      for (int ks = 0; ks < 2; ++ks)
        bf1[n][ks] = *reinterpret_cast<const bf16x8*>(base + boff(1, n, ks));
    __builtin_amdgcn_s_setprio(1);
#pragma unroll
    for (int m = 0; m < MQ; ++m)
#pragma unroll
      for (int n = 0; n < 2; ++n)
#pragma unroll
        for (int ks = 0; ks < 2; ++ks)
          acc[m][2 + n] = __builtin_amdgcn_mfma_f32_16x16x32_bf16(af[m][ks], bf1[n][ks], acc[m][2 + n], 0, 0, 0);
    __builtin_amdgcn_s_setprio(0);
    // q2
#pragma unroll
    for (int m = 0; m < MQ; ++m)
#pragma unroll
      for (int ks = 0; ks < 2; ++ks)
        af[m][ks] = *reinterpret_cast<const bf16x8*>(base + aoff(1, m, ks));
    __builtin_amdgcn_s_setprio(1);
#pragma unroll
    for (int m = 0; m < MQ; ++m)
#pragma unroll
      for (int n = 0; n < 2; ++n)
#pragma unroll
        for (int ks = 0; ks < 2; ++ks)
          acc[MQ + m][n] = __builtin_amdgcn_mfma_f32_16x16x32_bf16(af[m][ks], bf0[n][ks], acc[MQ + m][n], 0, 0, 0);
    __builtin_amdgcn_s_setprio(0);
    // q3
    __builtin_amdgcn_s_setprio(1);
#pragma unroll
    for (int m = 0; m < MQ; ++m)
#pragma unroll
      for (int n = 0; n < 2; ++n)
#pragma unroll
        for (int ks = 0; ks < 2; ++ks)
          acc[MQ + m][2 + n] = __builtin_amdgcn_mfma_f32_16x16x32_bf16(af[m][ks], bf1[n][ks], acc[MQ + m][2 + n], 0, 0, 0);
    __builtin_amdgcn_s_setprio(0);
  };

  for (int t = 0; t < nt; t += 2) {
    tileStep(t, bO, bE);      // writes B(t+1) from bO, loads B(t+2) into bE
    tileStep(t + 1, bE, bO);  // writes B(t+2) from bE, loads B(t+3) into bO
  }

  // epilogue: bias + store
#pragma unroll
  for (int ni = 0; ni < 4; ++ni) {
    int col = bn + wc * 64 + ni * 16 + lrow;
    float bv = bias[col];
#pragma unroll
    for (int mi = 0; mi < 2 * MQ; ++mi)
#pragma unroll
      for (int r = 0; r < 4; ++r) {
        int row = bm + wr * (BM / 2) + mi * 16 + lgrp * 4 + r;
        if constexpr (OBF)
          ((unsigned short*)Cp)[(size_t)row * N + col] = f32_bf16(acc[mi][ni][r] + bv);
        else
          ((float*)Cp)[(size_t)row * N + col] = acc[mi][ni][r] + bv;
      }
  }
}

// ---------------- RoPE + split (bf16 qkv input), vectorized ------------------
__global__ __launch_bounds__(256) void rope_split(const unsigned short* __restrict__ qkvb,
                                                  const float* __restrict__ ct,
                                                  const float* __restrict__ st,
                                                  unsigned short* __restrict__ Q,
                                                  unsigned short* __restrict__ Kh,
                                                  unsigned short* __restrict__ Vt) {
  int b = blockIdx.x;
  if (b < 5120) {
    int t = b * 256 + threadIdx.x;
    int d8 = (t & 15) * 8;
    int q = t >> 4;
    int s = q / 40;
    int slotg = q - s * 40;
    int g = slotg / 5, slot = slotg - g * 5;
    const unsigned short* base = qkvb + (size_t)s * QKV_OUT + g * 768 + slot * 128;
    bf16x8 x8 = *reinterpret_cast<const bf16x8*>(base + d8);
    bf16x8 r8 = *reinterpret_cast<const bf16x8*>(base + (d8 ^ 64));
    float4 c0 = *reinterpret_cast<const float4*>(ct + s * 64 + (d8 & 63));
    float4 c1 = *reinterpret_cast<const float4*>(ct + s * 64 + (d8 & 63) + 4);
    float4 s0 = *reinterpret_cast<const float4*>(st + s * 64 + (d8 & 63));
    float4 s1 = *reinterpret_cast<const float4*>(st + s * 64 + (d8 & 63) + 4);
    float cc[8] = {c0.x, c0.y, c0.z, c0.w, c1.x, c1.y, c1.z, c1.w};
    float ss[8] = {s0.x, s0.y, s0.z, s0.w, s1.x, s1.y, s1.z, s1.w};
    float sgn = (d8 < 64) ? -1.0f : 1.0f;
    float sc = (slot < 4) ? QSCALE : 1.0f;
    unsigned short o[8];
#pragma unroll
    for (int i = 0; i < 8; ++i) {
      float x = bf16_f32((unsigned short)x8[i]);
      float r = bf16_f32((unsigned short)r8[i]) * sgn;
      o[i] = f32_bf16((x * cc[i] + r * ss[i]) * sc);
    }
    unsigned short* dst = (slot < 4)
        ? Q + ((size_t)(g * 4 + slot) * SEQ + s) * HD + d8
        : Kh + ((size_t)g * SEQ + s) * HD + d8;
    *reinterpret_cast<uint4*>(dst) = *reinterpret_cast<uint4*>(o);
  } else {
    int t2 = (b - 5120) * 256 + threadIdx.x;
    int d = t2 & 127;
    int rest = t2 >> 7;
    int g = rest & 7;
    int s0 = (rest >> 3) * 8;
    const unsigned short* src = qkvb + (size_t)s0 * QKV_OUT + g * 768 + 640 + d;
    unsigned short o[8];
#pragma unroll
    for (int i = 0; i < 8; ++i) o[i] = src[(size_t)i * QKV_OUT];
    *reinterpret_cast<uint4*>(&Vt[((size_t)g * HD + d) * SEQ + s0]) =
        *reinterpret_cast<uint4*>(o);
  }
}

// next valid blocksparse j >= x for this qb (uniform across block), -1 if none.
__device__ inline int nextj(int x, int qb) {
  if (x > qb) return -1;
  if (qb - x < 16) return x;
  int v = (x & ~7) + 7;
  int w = qb - 15;
  return v < w ? v : w;
}

// ---------------- blocksparse flash attention (unchanged, R8-passing) --------
__global__ __launch_bounds__(256, 2) void attn32(const unsigned short* __restrict__ Q,
                                                 const unsigned short* __restrict__ Kh,
                                                 const unsigned short* __restrict__ Vt,
                                                 unsigned short* __restrict__ ctx) {
  const int g = blockIdx.x;
  const int y = (int)gridDim.y - 1 - (int)blockIdx.y;
  const int qb = y >> 1, half = y & 1;
  const int Q0 = y * 32;
  const int tid = threadIdx.x;
  const int wave = tid >> 6;
  const int h = g * 4 + wave;
  const int lane = tid & 63;
  const int l31 = lane & 31, hi = lane >> 5;

  __shared__ __align__(16) char Lds[65536];

  auto stage = [&](int bufb, int j) {
#pragma unroll
    for (int i = 0; i < 4; ++i) {
      int row = i * 16 + (tid >> 4);
      const unsigned short* src =
          Kh + ((size_t)(g * SEQ + j * 64 + row)) * HD + ((tid & 15) ^ (row & 15)) * 8;
      __builtin_amdgcn_global_load_lds(
          (const __attribute__((address_space(1))) unsigned int*)src,
          (__attribute__((address_space(3))) unsigned int*)(Lds + bufb + i * 4096 + (tid >> 6) * 1024),
          16, 0, 0);
    }
#pragma unroll
    for (int i = 0; i < 4; ++i) {
      int row = i * 32 + (tid >> 3);
      const unsigned short* src =
          Vt + ((size_t)(g * HD + row)) * SEQ + j * 64 + ((tid & 7) ^ (row & 7)) * 8;
      __builtin_amdgcn_global_load_lds(
          (const __attribute__((address_space(1))) unsigned int*)src,
          (__attribute__((address_space(3))) unsigned int*)(Lds + bufb + 16384 + i * 4096 + (tid >> 6) * 1024),
          16, 0, 0);
    }
  };

  bf16x8 qf[8];
  const unsigned short* qbase = Q + ((size_t)h * SEQ + Q0 + l31) * HD;
#pragma unroll
  for (int kk = 0; kk < 8; ++kk)
    qf[kk] = *reinterpret_cast<const bf16x8*>(qbase + kk * 16 + hi * 8);

  f32x16 ot[4] = {};
  float mrow = -1e30f, lsum = 0.f;

  const int kswz = l31 & 15;
  const int vswz = l31 & 7;

  int j = nextj(0, qb);
  int cur = 0;
  stage(0, j);
  asm volatile("s_waitcnt vmcnt(0)" ::: "memory");
  __builtin_amdgcn_sched_barrier(0);
  __builtin_amdgcn_s_barrier();
  __builtin_amdgcn_sched_barrier(0);

  while (true) {
    const int jn = (j < qb) ? nextj(j + 1, qb) : -1;
    if (jn >= 0) stage(cur ^ 32768, jn);

    const char* kb = Lds + cur;
    const char* vb = Lds + cur + 16384;
    const bool diag = (j == qb);
    const bool short_blk = diag && (half == 0);

    f32x16 st[2] = {};
    __builtin_amdgcn_s_setprio(1);
#pragma unroll
    for (int kk = 0; kk < 8; ++kk) {
      bf16x8 k0 = *reinterpret_cast<const bf16x8*>(
          kb + (size_t)l31 * 256 + (((2 * kk + hi) ^ kswz) * 16));
      st[0] = __builtin_amdgcn_mfma_f32_32x32x16_bf16(k0, qf[kk], st[0], 0, 0, 0);
      if (!short_blk) {
        bf16x8 k1 = *reinterpret_cast<const bf16x8*>(
            kb + (size_t)(32 + l31) * 256 + (((2 * kk + hi) ^ kswz) * 16));
        st[1] = __builtin_amdgcn_mfma_f32_32x32x16_bf16(k1, qf[kk], st[1], 0, 0, 0);
      }
    }
    __builtin_amdgcn_s_setprio(0);

    if (diag) {
      int qrel = half * 32 + l31;
#pragma unroll
      for (int kt = 0; kt < 2; ++kt)
#pragma unroll
        for (int r = 0; r < 16; ++r) {
          int krel = kt * 32 + (r & 3) + 8 * (r >> 2) + 4 * hi;
          if (krel > qrel) st[kt][r] = -1e30f;
        }
    }

    float t16[16];
#pragma unroll
    for (int r = 0; r < 16; ++r) t16[r] = fmaxf(st[0][r], st[1][r]);
#pragma unroll
    for (int sft = 8; sft >= 1; sft >>= 1)
#pragma unroll
      for (int r = 0; r < sft; ++r) t16[r] = fmaxf(t16[r], t16[r + sft]);
    float vm = xmax32(t16[0]);

    if (!__all(vm - mrow <= 8.0f)) {
      float nm = fmaxf(mrow, vm);
      float corr = __builtin_amdgcn_exp2f(mrow - nm);
      lsum *= corr;
#pragma unroll
      for (int dt = 0; dt < 4; ++dt)
#pragma unroll
        for (int r = 0; r < 16; ++r) ot[dt][r] *= corr;
      mrow = nm;
    }

    float s4[4] = {0.f, 0.f, 0.f, 0.f};
#pragma unroll
    for (int kt = 0; kt < 2; ++kt)
#pragma unroll
      for (int r = 0; r < 16; ++r) {
        float p = __builtin_amdgcn_exp2f(st[kt][r] - mrow);
        st[kt][r] = p;
        s4[r & 3] += p;
      }
    lsum += xadd32((s4[0] + s4[1]) + (s4[2] + s4[3]));

    bf16x8 pb[4];
#pragma unroll
    for (int s = 0; s < 4; ++s) {
      int kt = s >> 1, g0 = (s & 1) * 2, g1 = g0 + 1;
      unsigned int a0 = pk(st[kt][4 * g0 + 0], st[kt][4 * g0 + 1]);
      unsigned int a1 = pk(st[kt][4 * g0 + 2], st[kt][4 * g0 + 3]);
      unsigned int b0 = pk(st[kt][4 * g1 + 0], st[kt][4 * g1 + 1]);
      unsigned int b1 = pk(st[kt][4 * g1 + 2], st[kt][4 * g1 + 3]);
      pswap(a0, b0);
      pswap(a1, b1);
      union { unsigned int u[4]; bf16x8 v; } t;
      t.u[0] = a0; t.u[1] = a1; t.u[2] = b0; t.u[3] = b1;
      pb[s] = t.v;
    }

    const int smax = short_blk ? 2 : 4;
    __builtin_amdgcn_s_setprio(1);
#pragma unroll
    for (int dt = 0; dt < 4; ++dt) {
      const char* vrow = vb + (size_t)(dt * 32 + l31) * 128;
#pragma unroll
      for (int s = 0; s < 4; ++s)
        if (s < smax)
          ot[dt] = __builtin_amdgcn_mfma_f32_32x32x16_bf16(
              *reinterpret_cast<const bf16x8*>(vrow + (((2 * s + hi) ^ vswz) * 16)),
              pb[s], ot[dt], 0, 0, 0);
    }
    __builtin_amdgcn_s_setprio(0);

    if (jn < 0) break;
    asm volatile("s_waitcnt vmcnt(0)" ::: "memory");
    __builtin_amdgcn_sched_barrier(0);
    __builtin_amdgcn_s_barrier();
    __builtin_amdgcn_sched_barrier(0);
    j = jn;
    cur ^= 32768;
  }

  __syncthreads();
  char* W = Lds + wave * 8192;
  float inv = 1.0f / lsum;
  const int swz = (l31 & 7) << 4;
#pragma unroll
  for (int dt = 0; dt < 4; ++dt)
#pragma unroll
    for (int gg = 0; gg < 4; ++gg) {
      unsigned int u0 = pk(ot[dt][4 * gg + 0] * inv, ot[dt][4 * gg + 1] * inv);
      unsigned int u1 = pk(ot[dt][4 * gg + 2] * inv, ot[dt][4 * gg + 3] * inv);
      int off = (dt * 64 + gg * 16 + hi * 8) ^ swz;
      *reinterpret_cast<uint2*>(W + l31 * 256 + off) = make_uint2(u0, u1);
    }
#pragma unroll
  for (int i = 0; i < 8; ++i) {
    int row = lane >> 1;
    int t = (lane & 1) * 8 + i;
    bf16x8 vv = *reinterpret_cast<const bf16x8*>(
        W + row * 256 + ((t * 16) ^ ((row & 7) << 4)));
    *reinterpret_cast<bf16x8*>(&ctx[(size_t)(Q0 + row) * HIDDEN + h * HD + t * 8]) = vv;
  }
}

extern "C" void kernel_launch(void* const* d_in, const int* in_sizes, int n_in,
                              void* d_out, int out_size, void* d_ws, size_t ws_size,
                              hipStream_t stream) {
  const float* hidden  = (const float*)d_in[0];
  const float* w_qkv   = (const float*)d_in[1];
  const float* b_qkv   = (const float*)d_in[2];
  const float* w_dense = (const float*)d_in[3];
  const float* b_dense = (const float*)d_in[4];
  float* out = (float*)d_out;

  char* p = (char*)d_ws;
  unsigned short* hid_bf  = (unsigned short*)p; p += (size_t)SEQ * HIDDEN * 2;
  unsigned short* qkvb    = (unsigned short*)p; p += (size_t)SEQ * QKV_OUT * 2;
  unsigned short* Qb      = (unsigned short*)p; p += (size_t)NH * SEQ * HD * 2;
  unsigned short* Kb      = (unsigned short*)p; p += (size_t)NKV * SEQ * HD * 2;
  unsigned short* Vt      = (unsigned short*)p; p += (size_t)NKV * HD * SEQ * 2;
  float* ct               = (float*)p;          p += (size_t)SEQ * 64 * 4;
  float* st               = (float*)p;          p += (size_t)SEQ * 64 * 4;
  unsigned short* ctx = hid_bf;  // hidden_bf16 dead after QKV GEMM

  conv_bf16<<<(SEQ * HIDDEN) / 2048, 256, 0, stream>>>(hidden, hid_bf, SEQ * HIDDEN);
  build_tab<<<(SEQ * 64) / 256, 256, 0, stream>>>(ct, st);

  // QKV: 128x256 tiles -> grid 16x24 = 384 blocks, XCD chunk 8x6, bf16 out.
  gemmW<8, 6, true>
      <<<dim3((SEQ / 128) * (QKV_OUT / 256)), 512, 0, stream>>>(
          hid_bf, w_qkv, b_qkv, qkvb, SEQ, QKV_OUT, HIDDEN);
  rope_split<<<5120 + 1024, 256, 0, stream>>>(qkvb, ct, st, Qb, Kb, Vt);
  attn32<<<dim3(NKV, SEQ / 32), 256, 0, stream>>>(Qb, Kb, Vt, ctx);
  // dense: 128x256 tiles -> grid 16x16 = 256 blocks, XCD chunk 8x4, fp32 out.
  gemmW<8, 4, false>
      <<<dim3((SEQ / 128) * (HIDDEN / 256)), 512, 0, stream>>>(
          ctx, w_dense, b_dense, out, SEQ, HIDDEN, HIDDEN);
}

// Round 15
// 299.433 us; speedup vs baseline: 1.1709x; 1.1709x over previous
//
#include <hip/hip_runtime.h>
#include <hip/hip_bf16.h>

#define SEQ 2048
#define HIDDEN 4096
#define NH 32
#define NKV 8
#define HD 128
#define QKV_OUT 6144   // (32 + 2*8) * 128
// Q is pre-scaled by SM_SCALE*log2(e) so softmax uses exp2 directly.
#define QSCALE (0.0078125f * 1.4426950408889634f)

typedef __attribute__((ext_vector_type(8))) short bf16x8;
typedef __attribute__((ext_vector_type(4))) float f32x4;
typedef __attribute__((ext_vector_type(16))) float f32x16;

__device__ inline unsigned short f32_bf16(float f) {
  union { float f; unsigned int u; } v; v.f = f;
  unsigned int r = v.u + 0x7FFFu + ((v.u >> 16) & 1u);
  return (unsigned short)(r >> 16);
}
__device__ inline float bf16_f32(unsigned short u) {
  union { unsigned int u; float f; } v; v.u = (unsigned int)u << 16;
  return v.f;
}
__device__ inline unsigned int pk(float a, float b) {
  union { __hip_bfloat162 h; unsigned int u; } t;
  t.h = __float22bfloat162_rn(make_float2(a, b));
  return t.u;
}
__device__ inline void pswap(unsigned int &a, unsigned int &b) {
  auto r = __builtin_amdgcn_permlane32_swap((int)a, (int)b, false, false);
  a = (unsigned int)r[0]; b = (unsigned int)r[1];
}
__device__ inline float xmax32(float v) {
  int x = __builtin_bit_cast(int, v);
  auto r = __builtin_amdgcn_permlane32_swap(x, x, false, false);
  return fmaxf(__builtin_bit_cast(float, (int)r[0]), __builtin_bit_cast(float, (int)r[1]));
}
__device__ inline float xadd32(float v) {
  int x = __builtin_bit_cast(int, v);
  auto r = __builtin_amdgcn_permlane32_swap(x, x, false, false);
  return __builtin_bit_cast(float, (int)r[0]) + __builtin_bit_cast(float, (int)r[1]);
}

__device__ inline void cast8(const float* __restrict__ in, unsigned short* __restrict__ out) {
  float4 a = *reinterpret_cast<const float4*>(in);
  float4 b = *reinterpret_cast<const float4*>(in + 4);
  unsigned short t[8];
  t[0] = f32_bf16(a.x); t[1] = f32_bf16(a.y); t[2] = f32_bf16(a.z); t[3] = f32_bf16(a.w);
  t[4] = f32_bf16(b.x); t[5] = f32_bf16(b.y); t[6] = f32_bf16(b.z); t[7] = f32_bf16(b.w);
  *reinterpret_cast<uint4*>(out) = *reinterpret_cast<uint4*>(t);
}

// ---------------- prep: conv1 (hidden) + conv2 (w_qkv) + RoPE tables ---------
#define N1 ((size_t)SEQ * HIDDEN / 8)        // 1,048,576
#define N2 ((size_t)QKV_OUT * HIDDEN / 8)    // 3,145,728
#define N3 ((size_t)SEQ * 64)                // 131,072
__global__ __launch_bounds__(256) void prep(const float* __restrict__ hid,
                                            unsigned short* __restrict__ hid_bf,
                                            const float* __restrict__ wq,
                                            unsigned short* __restrict__ wq_bf,
                                            float* __restrict__ ct,
                                            float* __restrict__ st) {
  size_t i = (size_t)blockIdx.x * 256 + threadIdx.x;
  if (i < N1) {
    cast8(hid + i * 8, hid_bf + i * 8);
  } else if (i < N1 + N2) {
    size_t j = (i - N1) * 8;
    cast8(wq + j, wq_bf + j);
  } else {
    size_t j = i - N1 - N2;  // < N3
    int s = (int)(j >> 6), d = (int)(j & 63);
    float inv = powf(1.0e6f, -(float)d * (1.0f / 64.0f));
    float f = (float)s * inv;
    ct[j] = cosf(f);
    st[j] = sinf(f);
  }
}

// ---------------- 4-phase/1-barrier GEMM (R11 gemm9) + optional fused conv ---
// BN=256 fixed. 512 threads = 8 waves (2M x 4N), per-wave C = (BM/2) x 64.
// FC: blocks >= ngemm instead run a grid-stride fp32->bf16 cast (w_dense),
// filling the CUs left idle by the gemm's 1.5-round occupancy.
template <int BM, int CR, int CC, bool OBF, bool FC>
__global__ __launch_bounds__(512, 2) void gemm9(const unsigned short* __restrict__ A,
                                                const unsigned short* __restrict__ B,
                                                const float* __restrict__ bias,
                                                void* __restrict__ Cp,
                                                int M, int N, int K,
                                                const float* __restrict__ cw_in,
                                                unsigned short* __restrict__ cw_out,
                                                size_t cw_n, int ngemm) {
  constexpr int BN = 256;
  constexpr int MQ = BM / 64;
  constexpr int La = BM / 128;
  constexpr int Lb = 2;
  constexpr int AH = BM * 64;
  constexpr int BUF = AH * 2 + 32768;
  __shared__ __align__(16) char Lds[BUF * 2];

  if constexpr (FC) {
    if ((int)blockIdx.x >= ngemm) {
      size_t base = ((size_t)(blockIdx.x - ngemm) * 512 + threadIdx.x) * 8;
      size_t stride = (size_t)(gridDim.x - ngemm) * 512 * 8;
      for (size_t i = base; i < cw_n; i += stride)
        cast8(cw_in + i, cw_out + i);
      return;
    }
  }

  const int tid = threadIdx.x;
  const int wave = tid >> 6, lane = tid & 63;
  const int wr = wave >> 2, wc = wave & 3;
  const int lrow = lane & 15, lgrp = lane >> 4;

  // 2D XCD chunk
  const int ntx = N / BN;
  const int wg0 = blockIdx.x;
  const int xcd = wg0 & 7, w = wg0 >> 3;
  const int cpb = ntx / CC;
  const int band = xcd / cpb, colc = xcd % cpb;
  const int bm = (band * CR + w / CC) * BM;
  const int bn = (colc * CC + w % CC) * BN;

  const int srow8 = lane >> 3;
  const int scol = ((lane & 7) ^ srow8) * 8;
  const unsigned short* gsrc[2 * La + 2 * Lb];
  int ldsoff[2 * La + 2 * Lb];
#pragma unroll
  for (int u = 0; u < 2; ++u)
#pragma unroll
    for (int j = 0; j < La; ++j) {
      int row = bm + u * (BM / 2) + (wave * La + j) * 8 + srow8;
      gsrc[u * La + j] = A + (size_t)row * K + scol;
      ldsoff[u * La + j] = u * AH + (wave * La + j) * 1024;
    }
#pragma unroll
  for (int u = 0; u < 2; ++u)
#pragma unroll
    for (int j = 0; j < Lb; ++j) {
      int row = bn + u * 128 + (wave * Lb + j) * 8 + srow8;
      gsrc[2 * La + u * Lb + j] = B + (size_t)row * K + scol;
      ldsoff[2 * La + u * Lb + j] = 2 * AH + u * 16384 + (wave * Lb + j) * 1024;
    }

  auto stage = [&](int bufb, int u, int k0) {
    const int lo = (u < 2) ? u * La : 2 * La + (u - 2) * Lb;
    const int nl = (u < 2) ? La : Lb;
#pragma unroll
    for (int j = 0; j < 4; ++j)
      if (j < nl)
        __builtin_amdgcn_global_load_lds(
            (const __attribute__((address_space(1))) unsigned int*)(gsrc[lo + j] + k0),
            (__attribute__((address_space(3))) unsigned int*)(Lds + bufb + ldsoff[lo + j]),
            16, 0, 0);
  };

  const int rsw = (lrow & 7) << 4;
  auto aoff = [&](int mh, int m, int ks) {
    int r = mh * (BM / 4) + m * 16 + lrow;
    return wr * AH + r * 128 + ((ks * 64 + lgrp * 16) ^ rsw);
  };
  auto boff = [&](int nh, int n, int ks) {
    int r = (wc & 1) * 64 + nh * 32 + n * 16 + lrow;
    return 2 * AH + (wc >> 1) * 16384 + r * 128 + ((ks * 64 + lgrp * 16) ^ rsw);
  };

  f32x4 acc[2 * MQ][4] = {};
  bf16x8 af[MQ][2], bf0[2][2], bf1[2][2];

  const int nt = K / 64;
#pragma unroll
  for (int u = 0; u < 4; ++u) stage(0, u, 0);

  for (int t = 0; t < nt; ++t) {
    const int cur = (t & 1) ? BUF : 0;
    const int nxt = cur ^ BUF;
    const bool pf = (t + 1) < nt;
    const int k1 = (t + 1) * 64;
    const char* base = Lds + cur;

    // ---- q0: the one wait + barrier per tile ----
    if (pf) stage(nxt, 0, k1);
    if (pf) { if constexpr (La == 2) asm volatile("s_waitcnt vmcnt(2)" ::: "memory");
              else                   asm volatile("s_waitcnt vmcnt(1)" ::: "memory"); }
    else      asm volatile("s_waitcnt vmcnt(0)" ::: "memory");
    __builtin_amdgcn_sched_barrier(0);
    __builtin_amdgcn_s_barrier();
    __builtin_amdgcn_sched_barrier(0);
#pragma unroll
    for (int m = 0; m < MQ; ++m)
#pragma unroll
      for (int ks = 0; ks < 2; ++ks)
        af[m][ks] = *reinterpret_cast<const bf16x8*>(base + aoff(0, m, ks));
#pragma unroll
    for (int n = 0; n < 2; ++n)
#pragma unroll
      for (int ks = 0; ks < 2; ++ks)
        bf0[n][ks] = *reinterpret_cast<const bf16x8*>(base + boff(0, n, ks));
    __builtin_amdgcn_s_setprio(1);
#pragma unroll
    for (int m = 0; m < MQ; ++m)
#pragma unroll
      for (int n = 0; n < 2; ++n)
#pragma unroll
        for (int ks = 0; ks < 2; ++ks)
          acc[m][n] = __builtin_amdgcn_mfma_f32_16x16x32_bf16(af[m][ks], bf0[n][ks], acc[m][n], 0, 0, 0);
    __builtin_amdgcn_s_setprio(0);

    // ---- q1 ----
    if (pf) stage(nxt, 1, k1);
#pragma unroll
    for (int n = 0; n < 2; ++n)
#pragma unroll
      for (int ks = 0; ks < 2; ++ks)
        bf1[n][ks] = *reinterpret_cast<const bf16x8*>(base + boff(1, n, ks));
    __builtin_amdgcn_s_setprio(1);
#pragma unroll
    for (int m = 0; m < MQ; ++m)
#pragma unroll
      for (int n = 0; n < 2; ++n)
#pragma unroll
        for (int ks = 0; ks < 2; ++ks)
          acc[m][2 + n] = __builtin_amdgcn_mfma_f32_16x16x32_bf16(af[m][ks], bf1[n][ks], acc[m][2 + n], 0, 0, 0);
    __builtin_amdgcn_s_setprio(0);

    // ---- q2 ----
    if (pf) stage(nxt, 2, k1);
#pragma unroll
    for (int m = 0; m < MQ; ++m)
#pragma unroll
      for (int ks = 0; ks < 2; ++ks)
        af[m][ks] = *reinterpret_cast<const bf16x8*>(base + aoff(1, m, ks));
    __builtin_amdgcn_s_setprio(1);
#pragma unroll
    for (int m = 0; m < MQ; ++m)
#pragma unroll
      for (int n = 0; n < 2; ++n)
#pragma unroll
        for (int ks = 0; ks < 2; ++ks)
          acc[MQ + m][n] = __builtin_amdgcn_mfma_f32_16x16x32_bf16(af[m][ks], bf0[n][ks], acc[MQ + m][n], 0, 0, 0);
    __builtin_amdgcn_s_setprio(0);

    // ---- q3 ----
    if (pf) stage(nxt, 3, k1);
    __builtin_amdgcn_s_setprio(1);
#pragma unroll
    for (int m = 0; m < MQ; ++m)
#pragma unroll
      for (int n = 0; n < 2; ++n)
#pragma unroll
        for (int ks = 0; ks < 2; ++ks)
          acc[MQ + m][2 + n] = __builtin_amdgcn_mfma_f32_16x16x32_bf16(af[m][ks], bf1[n][ks], acc[MQ + m][2 + n], 0, 0, 0);
    __builtin_amdgcn_s_setprio(0);
  }

  // epilogue: bias + store
#pragma unroll
  for (int ni = 0; ni < 4; ++ni) {
    int col = bn + wc * 64 + ni * 16 + lrow;
    float bv = bias[col];
#pragma unroll
    for (int mi = 0; mi < 2 * MQ; ++mi)
#pragma unroll
      for (int r = 0; r < 4; ++r) {
        int row = bm + wr * (BM / 2) + mi * 16 + lgrp * 4 + r;
        if constexpr (OBF)
          ((unsigned short*)Cp)[(size_t)row * N + col] = f32_bf16(acc[mi][ni][r] + bv);
        else
          ((float*)Cp)[(size_t)row * N + col] = acc[mi][ni][r] + bv;
      }
  }
}

// ---------------- RoPE + split (bf16 qkv input), vectorized ------------------
__global__ __launch_bounds__(256) void rope_split(const unsigned short* __restrict__ qkvb,
                                                  const float* __restrict__ ct,
                                                  const float* __restrict__ st,
                                                  unsigned short* __restrict__ Q,
                                                  unsigned short* __restrict__ Kh,
                                                  unsigned short* __restrict__ Vt) {
  int b = blockIdx.x;
  if (b < 5120) {
    int t = b * 256 + threadIdx.x;
    int d8 = (t & 15) * 8;
    int q = t >> 4;
    int s = q / 40;
    int slotg = q - s * 40;
    int g = slotg / 5, slot = slotg - g * 5;
    const unsigned short* base = qkvb + (size_t)s * QKV_OUT + g * 768 + slot * 128;
    bf16x8 x8 = *reinterpret_cast<const bf16x8*>(base + d8);
    bf16x8 r8 = *reinterpret_cast<const bf16x8*>(base + (d8 ^ 64));
    float4 c0 = *reinterpret_cast<const float4*>(ct + s * 64 + (d8 & 63));
    float4 c1 = *reinterpret_cast<const float4*>(ct + s * 64 + (d8 & 63) + 4);
    float4 s0 = *reinterpret_cast<const float4*>(st + s * 64 + (d8 & 63));
    float4 s1 = *reinterpret_cast<const float4*>(st + s * 64 + (d8 & 63) + 4);
    float cc[8] = {c0.x, c0.y, c0.z, c0.w, c1.x, c1.y, c1.z, c1.w};
    float ss[8] = {s0.x, s0.y, s0.z, s0.w, s1.x, s1.y, s1.z, s1.w};
    float sgn = (d8 < 64) ? -1.0f : 1.0f;
    float sc = (slot < 4) ? QSCALE : 1.0f;
    unsigned short o[8];
#pragma unroll
    for (int i = 0; i < 8; ++i) {
      float x = bf16_f32((unsigned short)x8[i]);
      float r = bf16_f32((unsigned short)r8[i]) * sgn;
      o[i] = f32_bf16((x * cc[i] + r * ss[i]) * sc);
    }
    unsigned short* dst = (slot < 4)
        ? Q + ((size_t)(g * 4 + slot) * SEQ + s) * HD + d8
        : Kh + ((size_t)g * SEQ + s) * HD + d8;
    *reinterpret_cast<uint4*>(dst) = *reinterpret_cast<uint4*>(o);
  } else {
    int t2 = (b - 5120) * 256 + threadIdx.x;
    int d = t2 & 127;
    int rest = t2 >> 7;
    int g = rest & 7;
    int s0 = (rest >> 3) * 8;
    const unsigned short* src = qkvb + (size_t)s0 * QKV_OUT + g * 768 + 640 + d;
    unsigned short o[8];
#pragma unroll
    for (int i = 0; i < 8; ++i) o[i] = src[(size_t)i * QKV_OUT];
    *reinterpret_cast<uint4*>(&Vt[((size_t)g * HD + d) * SEQ + s0]) =
        *reinterpret_cast<uint4*>(o);
  }
}

// next valid blocksparse j >= x for this qb (uniform across block), -1 if none.
__device__ inline int nextj(int x, int qb) {
  if (x > qb) return -1;
  if (qb - x < 16) return x;
  int v = (x & ~7) + 7;
  int w = qb - 15;
  return v < w ? v : w;
}

// ---------------- blocksparse flash attention (unchanged, R8-passing) --------
__global__ __launch_bounds__(256, 2) void attn32(const unsigned short* __restrict__ Q,
                                                 const unsigned short* __restrict__ Kh,
                                                 const unsigned short* __restrict__ Vt,
                                                 unsigned short* __restrict__ ctx) {
  const int g = blockIdx.x;
  const int y = (int)gridDim.y - 1 - (int)blockIdx.y;
  const int qb = y >> 1, half = y & 1;
  const int Q0 = y * 32;
  const int tid = threadIdx.x;
  const int wave = tid >> 6;
  const int h = g * 4 + wave;
  const int lane = tid & 63;
  const int l31 = lane & 31, hi = lane >> 5;

  __shared__ __align__(16) char Lds[65536];

  auto stage = [&](int bufb, int j) {
#pragma unroll
    for (int i = 0; i < 4; ++i) {
      int row = i * 16 + (tid >> 4);
      const unsigned short* src =
          Kh + ((size_t)(g * SEQ + j * 64 + row)) * HD + ((tid & 15) ^ (row & 15)) * 8;
      __builtin_amdgcn_global_load_lds(
          (const __attribute__((address_space(1))) unsigned int*)src,
          (__attribute__((address_space(3))) unsigned int*)(Lds + bufb + i * 4096 + (tid >> 6) * 1024),
          16, 0, 0);
    }
#pragma unroll
    for (int i = 0; i < 4; ++i) {
      int row = i * 32 + (tid >> 3);
      const unsigned short* src =
          Vt + ((size_t)(g * HD + row)) * SEQ + j * 64 + ((tid & 7) ^ (row & 7)) * 8;
      __builtin_amdgcn_global_load_lds(
          (const __attribute__((address_space(1))) unsigned int*)src,
          (__attribute__((address_space(3))) unsigned int*)(Lds + bufb + 16384 + i * 4096 + (tid >> 6) * 1024),
          16, 0, 0);
    }
  };

  bf16x8 qf[8];
  const unsigned short* qbase = Q + ((size_t)h * SEQ + Q0 + l31) * HD;
#pragma unroll
  for (int kk = 0; kk < 8; ++kk)
    qf[kk] = *reinterpret_cast<const bf16x8*>(qbase + kk * 16 + hi * 8);

  f32x16 ot[4] = {};
  float mrow = -1e30f, lsum = 0.f;

  const int kswz = l31 & 15;
  const int vswz = l31 & 7;

  int j = nextj(0, qb);
  int cur = 0;
  stage(0, j);
  asm volatile("s_waitcnt vmcnt(0)" ::: "memory");
  __builtin_amdgcn_sched_barrier(0);
  __builtin_amdgcn_s_barrier();
  __builtin_amdgcn_sched_barrier(0);

  while (true) {
    const int jn = (j < qb) ? nextj(j + 1, qb) : -1;
    if (jn >= 0) stage(cur ^ 32768, jn);

    const char* kb = Lds + cur;
    const char* vb = Lds + cur + 16384;
    const bool diag = (j == qb);
    const bool short_blk = diag && (half == 0);

    f32x16 st[2] = {};
    __builtin_amdgcn_s_setprio(1);
#pragma unroll
    for (int kk = 0; kk < 8; ++kk) {
      bf16x8 k0 = *reinterpret_cast<const bf16x8*>(
          kb + (size_t)l31 * 256 + (((2 * kk + hi) ^ kswz) * 16));
      st[0] = __builtin_amdgcn_mfma_f32_32x32x16_bf16(k0, qf[kk], st[0], 0, 0, 0);
      if (!short_blk) {
        bf16x8 k1 = *reinterpret_cast<const bf16x8*>(
            kb + (size_t)(32 + l31) * 256 + (((2 * kk + hi) ^ kswz) * 16));
        st[1] = __builtin_amdgcn_mfma_f32_32x32x16_bf16(k1, qf[kk], st[1], 0, 0, 0);
      }
    }
    __builtin_amdgcn_s_setprio(0);

    if (diag) {
      int qrel = half * 32 + l31;
#pragma unroll
      for (int kt = 0; kt < 2; ++kt)
#pragma unroll
        for (int r = 0; r < 16; ++r) {
          int krel = kt * 32 + (r & 3) + 8 * (r >> 2) + 4 * hi;
          if (krel > qrel) st[kt][r] = -1e30f;
        }
    }

    float t16[16];
#pragma unroll
    for (int r = 0; r < 16; ++r) t16[r] = fmaxf(st[0][r], st[1][r]);
#pragma unroll
    for (int sft = 8; sft >= 1; sft >>= 1)
#pragma unroll
      for (int r = 0; r < sft; ++r) t16[r] = fmaxf(t16[r], t16[r + sft]);
    float vm = xmax32(t16[0]);

    if (!__all(vm - mrow <= 8.0f)) {
      float nm = fmaxf(mrow, vm);
      float corr = __builtin_amdgcn_exp2f(mrow - nm);
      lsum *= corr;
#pragma unroll
      for (int dt = 0; dt < 4; ++dt)
#pragma unroll
        for (int r = 0; r < 16; ++r) ot[dt][r] *= corr;
      mrow = nm;
    }

    float s4[4] = {0.f, 0.f, 0.f, 0.f};
#pragma unroll
    for (int kt = 0; kt < 2; ++kt)
#pragma unroll
      for (int r = 0; r < 16; ++r) {
        float p = __builtin_amdgcn_exp2f(st[kt][r] - mrow);
        st[kt][r] = p;
        s4[r & 3] += p;
      }
    lsum += xadd32((s4[0] + s4[1]) + (s4[2] + s4[3]));

    bf16x8 pb[4];
#pragma unroll
    for (int s = 0; s < 4; ++s) {
      int kt = s >> 1, g0 = (s & 1) * 2, g1 = g0 + 1;
      unsigned int a0 = pk(st[kt][4 * g0 + 0], st[kt][4 * g0 + 1]);
      unsigned int a1 = pk(st[kt][4 * g0 + 2], st[kt][4 * g0 + 3]);
      unsigned int b0 = pk(st[kt][4 * g1 + 0], st[kt][4 * g1 + 1]);
      unsigned int b1 = pk(st[kt][4 * g1 + 2], st[kt][4 * g1 + 3]);
      pswap(a0, b0);
      pswap(a1, b1);
      union { unsigned int u[4]; bf16x8 v; } t;
      t.u[0] = a0; t.u[1] = a1; t.u[2] = b0; t.u[3] = b1;
      pb[s] = t.v;
    }

    const int smax = short_blk ? 2 : 4;
    __builtin_amdgcn_s_setprio(1);
#pragma unroll
    for (int dt = 0; dt < 4; ++dt) {
      const char* vrow = vb + (size_t)(dt * 32 + l31) * 128;
#pragma unroll
      for (int s = 0; s < 4; ++s)
        if (s < smax)
          ot[dt] = __builtin_amdgcn_mfma_f32_32x32x16_bf16(
              *reinterpret_cast<const bf16x8*>(vrow + (((2 * s + hi) ^ vswz) * 16)),
              pb[s], ot[dt], 0, 0, 0);
    }
    __builtin_amdgcn_s_setprio(0);

    if (jn < 0) break;
    asm volatile("s_waitcnt vmcnt(0)" ::: "memory");
    __builtin_amdgcn_sched_barrier(0);
    __builtin_amdgcn_s_barrier();
    __builtin_amdgcn_sched_barrier(0);
    j = jn;
    cur ^= 32768;
  }

  __syncthreads();
  char* W = Lds + wave * 8192;
  float inv = 1.0f / lsum;
  const int swz = (l31 & 7) << 4;
#pragma unroll
  for (int dt = 0; dt < 4; ++dt)
#pragma unroll
    for (int gg = 0; gg < 4; ++gg) {
      unsigned int u0 = pk(ot[dt][4 * gg + 0] * inv, ot[dt][4 * gg + 1] * inv);
      unsigned int u1 = pk(ot[dt][4 * gg + 2] * inv, ot[dt][4 * gg + 3] * inv);
      int off = (dt * 64 + gg * 16 + hi * 8) ^ swz;
      *reinterpret_cast<uint2*>(W + l31 * 256 + off) = make_uint2(u0, u1);
    }
#pragma unroll
  for (int i = 0; i < 8; ++i) {
    int row = lane >> 1;
    int t = (lane & 1) * 8 + i;
    bf16x8 vv = *reinterpret_cast<const bf16x8*>(
        W + row * 256 + ((t * 16) ^ ((row & 7) << 4)));
    *reinterpret_cast<bf16x8*>(&ctx[(size_t)(Q0 + row) * HIDDEN + h * HD + t * 8]) = vv;
  }
}

extern "C" void kernel_launch(void* const* d_in, const int* in_sizes, int n_in,
                              void* d_out, int out_size, void* d_ws, size_t ws_size,
                              hipStream_t stream) {
  const float* hidden  = (const float*)d_in[0];
  const float* w_qkv   = (const float*)d_in[1];
  const float* b_qkv   = (const float*)d_in[2];
  const float* w_dense = (const float*)d_in[3];
  const float* b_dense = (const float*)d_in[4];
  float* out = (float*)d_out;

  char* p = (char*)d_ws;
  unsigned short* hid_bf  = (unsigned short*)p; p += (size_t)SEQ * HIDDEN * 2;
  unsigned short* wqkv_bf = (unsigned short*)p; p += (size_t)QKV_OUT * HIDDEN * 2;
  unsigned short* wd_bf   = (unsigned short*)p; p += (size_t)HIDDEN * HIDDEN * 2;
  unsigned short* qkvb    = (unsigned short*)p; p += (size_t)SEQ * QKV_OUT * 2;
  unsigned short* Qb      = (unsigned short*)p; p += (size_t)NH * SEQ * HD * 2;
  unsigned short* Kb      = (unsigned short*)p; p += (size_t)NKV * SEQ * HD * 2;
  unsigned short* Vt      = (unsigned short*)p; p += (size_t)NKV * HD * SEQ * 2;
  float* ct               = (float*)p;          p += (size_t)SEQ * 64 * 4;
  float* st               = (float*)p;          p += (size_t)SEQ * 64 * 4;
  unsigned short* ctx = hid_bf;  // hidden_bf16 dead after QKV GEMM

  // conv1 + conv2 + rope tables in one launch
  const int prep_blocks = (int)((N1 + N2 + N3 + 255) / 256);
  prep<<<prep_blocks, 256, 0, stream>>>(hidden, hid_bf, w_qkv, wqkv_bf, ct, st);

  // QKV gemm (384 blocks) + fused w_dense cast (192 filler blocks).
  const int ngemm_qkv = (SEQ / 128) * (QKV_OUT / 256);  // 384
  gemm9<128, 8, 6, true, true>
      <<<dim3(ngemm_qkv + 192), 512, 0, stream>>>(
          hid_bf, wqkv_bf, b_qkv, qkvb, SEQ, QKV_OUT, HIDDEN,
          w_dense, wd_bf, (size_t)HIDDEN * HIDDEN, ngemm_qkv);
  rope_split<<<5120 + 1024, 256, 0, stream>>>(qkvb, ct, st, Qb, Kb, Vt);
  attn32<<<dim3(NKV, SEQ / 32), 256, 0, stream>>>(Qb, Kb, Vt, ctx);
  gemm9<128, 8, 4, false, false>
      <<<dim3((SEQ / 128) * (HIDDEN / 256)), 512, 0, stream>>>(
          ctx, wd_bf, b_dense, out, SEQ, HIDDEN, HIDDEN,
          nullptr, nullptr, 0, 0);
}

// Round 16
// 274.726 us; speedup vs baseline: 1.2762x; 1.0899x over previous
//
#include <hip/hip_runtime.h>
#include <hip/hip_bf16.h>

#define SEQ 2048
#define HIDDEN 4096
#define NH 32
#define NKV 8
#define HD 128
#define QKV_OUT 6144   // (32 + 2*8) * 128
// Q is pre-scaled by SM_SCALE*log2(e) so softmax uses exp2 directly.
#define QSCALE (0.0078125f * 1.4426950408889634f)

typedef __attribute__((ext_vector_type(8))) short bf16x8;
typedef __attribute__((ext_vector_type(4))) float f32x4;
typedef __attribute__((ext_vector_type(16))) float f32x16;

__device__ inline unsigned short f32_bf16(float f) {
  union { float f; unsigned int u; } v; v.f = f;
  unsigned int r = v.u + 0x7FFFu + ((v.u >> 16) & 1u);
  return (unsigned short)(r >> 16);
}
__device__ inline float bf16_f32(unsigned short u) {
  union { unsigned int u; float f; } v; v.u = (unsigned int)u << 16;
  return v.f;
}
__device__ inline unsigned int pk(float a, float b) {
  union { __hip_bfloat162 h; unsigned int u; } t;
  t.h = __float22bfloat162_rn(make_float2(a, b));
  return t.u;
}
__device__ inline void pswap(unsigned int &a, unsigned int &b) {
  auto r = __builtin_amdgcn_permlane32_swap((int)a, (int)b, false, false);
  a = (unsigned int)r[0]; b = (unsigned int)r[1];
}
__device__ inline float xmax32(float v) {
  int x = __builtin_bit_cast(int, v);
  auto r = __builtin_amdgcn_permlane32_swap(x, x, false, false);
  return fmaxf(__builtin_bit_cast(float, (int)r[0]), __builtin_bit_cast(float, (int)r[1]));
}
__device__ inline float xadd32(float v) {
  int x = __builtin_bit_cast(int, v);
  auto r = __builtin_amdgcn_permlane32_swap(x, x, false, false);
  return __builtin_bit_cast(float, (int)r[0]) + __builtin_bit_cast(float, (int)r[1]);
}

__device__ inline void cast8(const float* __restrict__ in, unsigned short* __restrict__ out) {
  float4 a = *reinterpret_cast<const float4*>(in);
  float4 b = *reinterpret_cast<const float4*>(in + 4);
  unsigned short t[8];
  t[0] = f32_bf16(a.x); t[1] = f32_bf16(a.y); t[2] = f32_bf16(a.z); t[3] = f32_bf16(a.w);
  t[4] = f32_bf16(b.x); t[5] = f32_bf16(b.y); t[6] = f32_bf16(b.z); t[7] = f32_bf16(b.w);
  *reinterpret_cast<uint4*>(out) = *reinterpret_cast<uint4*>(t);
}

// ------- prep: conv(hidden) + conv(w_qkv) + conv(w_dense) + RoPE tables ------
#define N1 ((size_t)SEQ * HIDDEN / 8)        // 1,048,576
#define N2 ((size_t)QKV_OUT * HIDDEN / 8)    // 3,145,728
#define N4 ((size_t)HIDDEN * HIDDEN / 8)     // 2,097,152
#define N3 ((size_t)SEQ * 64)                // 131,072
__global__ __launch_bounds__(256) void prep(const float* __restrict__ hid,
                                            unsigned short* __restrict__ hid_bf,
                                            const float* __restrict__ wq,
                                            unsigned short* __restrict__ wq_bf,
                                            const float* __restrict__ wd,
                                            unsigned short* __restrict__ wd_bf,
                                            float* __restrict__ ct,
                                            float* __restrict__ st) {
  size_t i = (size_t)blockIdx.x * 256 + threadIdx.x;
  if (i < N1) {
    cast8(hid + i * 8, hid_bf + i * 8);
  } else if (i < N1 + N2) {
    size_t j = (i - N1) * 8;
    cast8(wq + j, wq_bf + j);
  } else if (i < N1 + N2 + N4) {
    size_t j = (i - N1 - N2) * 8;
    cast8(wd + j, wd_bf + j);
  } else {
    size_t j = i - N1 - N2 - N4;  // < N3
    int s = (int)(j >> 6), d = (int)(j & 63);
    float inv = powf(1.0e6f, -(float)d * (1.0f / 64.0f));
    float f = (float)s * inv;
    ct[j] = cosf(f);
    st[j] = sinf(f);
  }
}

// ---------------- generalized 4-phase/1-barrier GEMM (gemm9 family) ----------
// C[M,N] = A[M,K]*B[N,K]^T + bias. 512 threads = 8 waves (2M x 4N).
// BN=256 instantiation is index-identical to the proven R11 gemm9.
// Per 64-K tile: q0 stages A-half0(t+1) + the ONE counted vmcnt + ONE barrier;
// q1 stages A-half1; q2/q3 stage the B loads; frags register-resident.
// Zero-conflict swizzle: source chunk ^= row&7 (pre-swizzled global), read
// col ^= (lrow&7)<<4; all frag/staging row bases are multiples of 8.
template <int BM, int BN, int CR, int CC, bool OBF>
__global__ __launch_bounds__(512, 2) void gemmG(const unsigned short* __restrict__ A,
                                                const unsigned short* __restrict__ B,
                                                const float* __restrict__ bias,
                                                void* __restrict__ Cp,
                                                int M, int N, int K) {
  constexpr int MQ   = BM / 64;         // A frags per (wave, mh-half)
  constexpr int NREP = BN / 64;         // B frags per wave (wave cols = 16*NREP)
  constexpr int NB0  = (NREP + 1) / 2;  // frags computed in first n-phase
  constexpr int La   = BM / 128;        // A gloads per wave per half
  constexpr int NB   = BN / 64;         // B gloads per wave per tile
  constexpr int NBQ2 = (NB + 1) / 2;    // B gloads issued at q2 (rest at q3)
  constexpr int AH   = BM * 64;         // bytes per A-half section
  constexpr int SB   = 2 * AH + BN * 128;
  __shared__ __align__(16) char Lds[SB * 2];

  const int tid = threadIdx.x;
  const int wave = tid >> 6, lane = tid & 63;
  const int wr = wave >> 2, wc = wave & 3;
  const int lrow = lane & 15, lgrp = lane >> 4;

  // 2D XCD chunk
  const int ntx = N / BN;
  const int wg0 = blockIdx.x;
  const int xcd = wg0 & 7, w = wg0 >> 3;
  const int cpb = ntx / CC;
  const int band = xcd / cpb, colc = xcd % cpb;
  const int bm = (band * CR + w / CC) * BM;
  const int bn = (colc * CC + w % CC) * BN;

  const int r8 = lane >> 3;
  const int scol = ((lane & 7) ^ r8) * 8;  // pre-swizzled source chunk

  const unsigned short* gA[2][La]; int lA[2][La];
#pragma unroll
  for (int u = 0; u < 2; ++u)
#pragma unroll
    for (int j = 0; j < La; ++j) {
      int row = bm + u * (BM / 2) + wave * (BM / 16) + j * 8 + r8;
      gA[u][j] = A + (size_t)row * K + scol;
      lA[u][j] = u * AH + (wave * (BM / 16) + j * 8) * 128;
    }
  const unsigned short* gB[NB]; int lB[NB];
#pragma unroll
  for (int j = 0; j < NB; ++j) {
    int row = bn + wave * (BN / 8) + j * 8 + r8;
    gB[j] = B + (size_t)row * K + scol;
    lB[j] = 2 * AH + (wave * (BN / 8) + j * 8) * 128;
  }

  auto stageA = [&](int bufb, int u, int k0) {
#pragma unroll
    for (int j = 0; j < La; ++j)
      __builtin_amdgcn_global_load_lds(
          (const __attribute__((address_space(1))) unsigned int*)(gA[u][j] + k0),
          (__attribute__((address_space(3))) unsigned int*)(Lds + bufb + lA[u][j]), 16, 0, 0);
  };
  auto stageB = [&](int bufb, int jlo, int jhi, int k0) {
#pragma unroll
    for (int j = 0; j < NB; ++j)
      if (j >= jlo && j < jhi)
        __builtin_amdgcn_global_load_lds(
            (const __attribute__((address_space(1))) unsigned int*)(gB[j] + k0),
            (__attribute__((address_space(3))) unsigned int*)(Lds + bufb + lB[j]), 16, 0, 0);
  };

  const int rsw = (lrow & 7) << 4;
  auto aoff = [&](int mh, int m, int ks) {
    int r = mh * (BM / 4) + m * 16 + lrow;
    return wr * AH + r * 128 + ((ks * 64 + lgrp * 16) ^ rsw);
  };
  auto boff = [&](int nf, int ks) {
    int r = wc * (BN / 4) + nf * 16 + lrow;
    return 2 * AH + r * 128 + ((ks * 64 + lgrp * 16) ^ rsw);
  };

  f32x4 acc[2 * MQ][NREP] = {};
  bf16x8 af[MQ][2], bf[NREP][2];

  const int nt = K / 64;
  stageA(0, 0, 0);
  stageA(0, 1, 0);
  stageB(0, 0, NB, 0);

  for (int t = 0; t < nt; ++t) {
    const int cur = (t & 1) ? SB : 0;
    const int nxt = cur ^ SB;
    const bool pf = (t + 1) < nt;
    const int k1 = (t + 1) * 64;
    const char* base = Lds + cur;

    // ---- q0: the one counted wait + barrier per tile ----
    if (pf) stageA(nxt, 0, k1);
    if (pf) { if constexpr (La == 2) asm volatile("s_waitcnt vmcnt(2)" ::: "memory");
              else                   asm volatile("s_waitcnt vmcnt(1)" ::: "memory"); }
    else      asm volatile("s_waitcnt vmcnt(0)" ::: "memory");
    __builtin_amdgcn_sched_barrier(0);
    __builtin_amdgcn_s_barrier();
    __builtin_amdgcn_sched_barrier(0);
#pragma unroll
    for (int m = 0; m < MQ; ++m)
#pragma unroll
      for (int ks = 0; ks < 2; ++ks)
        af[m][ks] = *reinterpret_cast<const bf16x8*>(base + aoff(0, m, ks));
#pragma unroll
    for (int nf = 0; nf < NB0; ++nf)
#pragma unroll
      for (int ks = 0; ks < 2; ++ks)
        bf[nf][ks] = *reinterpret_cast<const bf16x8*>(base + boff(nf, ks));
    __builtin_amdgcn_s_setprio(1);
#pragma unroll
    for (int m = 0; m < MQ; ++m)
#pragma unroll
      for (int nf = 0; nf < NB0; ++nf)
#pragma unroll
        for (int ks = 0; ks < 2; ++ks)
          acc[m][nf] = __builtin_amdgcn_mfma_f32_16x16x32_bf16(af[m][ks], bf[nf][ks], acc[m][nf], 0, 0, 0);
    __builtin_amdgcn_s_setprio(0);

    // ---- q1 ----
    if (pf) stageA(nxt, 1, k1);
#pragma unroll
    for (int nf = NB0; nf < NREP; ++nf)
#pragma unroll
      for (int ks = 0; ks < 2; ++ks)
        bf[nf][ks] = *reinterpret_cast<const bf16x8*>(base + boff(nf, ks));
    __builtin_amdgcn_s_setprio(1);
#pragma unroll
    for (int m = 0; m < MQ; ++m)
#pragma unroll
      for (int nf = NB0; nf < NREP; ++nf)
#pragma unroll
        for (int ks = 0; ks < 2; ++ks)
          acc[m][nf] = __builtin_amdgcn_mfma_f32_16x16x32_bf16(af[m][ks], bf[nf][ks], acc[m][nf], 0, 0, 0);
    __builtin_amdgcn_s_setprio(0);

    // ---- q2 ----
    if (pf) stageB(nxt, 0, NBQ2, k1);
#pragma unroll
    for (int m = 0; m < MQ; ++m)
#pragma unroll
      for (int ks = 0; ks < 2; ++ks)
        af[m][ks] = *reinterpret_cast<const bf16x8*>(base + aoff(1, m, ks));
    __builtin_amdgcn_s_setprio(1);
#pragma unroll
    for (int m = 0; m < MQ; ++m)
#pragma unroll
      for (int nf = 0; nf < NB0; ++nf)
#pragma unroll
        for (int ks = 0; ks < 2; ++ks)
          acc[MQ + m][nf] = __builtin_amdgcn_mfma_f32_16x16x32_bf16(af[m][ks], bf[nf][ks], acc[MQ + m][nf], 0, 0, 0);
    __builtin_amdgcn_s_setprio(0);

    // ---- q3 ----
    if (pf) stageB(nxt, NBQ2, NB, k1);
    __builtin_amdgcn_s_setprio(1);
#pragma unroll
    for (int m = 0; m < MQ; ++m)
#pragma unroll
      for (int nf = NB0; nf < NREP; ++nf)
#pragma unroll
        for (int ks = 0; ks < 2; ++ks)
          acc[MQ + m][nf] = __builtin_amdgcn_mfma_f32_16x16x32_bf16(af[m][ks], bf[nf][ks], acc[MQ + m][nf], 0, 0, 0);
    __builtin_amdgcn_s_setprio(0);
  }

  // epilogue: bias + store
#pragma unroll
  for (int ni = 0; ni < NREP; ++ni) {
    int col = bn + wc * (BN / 4) + ni * 16 + lrow;
    float bv = bias[col];
#pragma unroll
    for (int mi = 0; mi < 2 * MQ; ++mi)
#pragma unroll
      for (int r = 0; r < 4; ++r) {
        int row = bm + wr * (BM / 2) + mi * 16 + lgrp * 4 + r;
        if constexpr (OBF)
          ((unsigned short*)Cp)[(size_t)row * N + col] = f32_bf16(acc[mi][ni][r] + bv);
        else
          ((float*)Cp)[(size_t)row * N + col] = acc[mi][ni][r] + bv;
      }
  }
}

// ---------------- RoPE + split (bf16 qkv input), vectorized ------------------
__global__ __launch_bounds__(256) void rope_split(const unsigned short* __restrict__ qkvb,
                                                  const float* __restrict__ ct,
                                                  const float* __restrict__ st,
                                                  unsigned short* __restrict__ Q,
                                                  unsigned short* __restrict__ Kh,
                                                  unsigned short* __restrict__ Vt) {
  int b = blockIdx.x;
  if (b < 5120) {
    int t = b * 256 + threadIdx.x;
    int d8 = (t & 15) * 8;
    int q = t >> 4;
    int s = q / 40;
    int slotg = q - s * 40;
    int g = slotg / 5, slot = slotg - g * 5;
    const unsigned short* base = qkvb + (size_t)s * QKV_OUT + g * 768 + slot * 128;
    bf16x8 x8 = *reinterpret_cast<const bf16x8*>(base + d8);
    bf16x8 r8 = *reinterpret_cast<const bf16x8*>(base + (d8 ^ 64));
    float4 c0 = *reinterpret_cast<const float4*>(ct + s * 64 + (d8 & 63));
    float4 c1 = *reinterpret_cast<const float4*>(ct + s * 64 + (d8 & 63) + 4);
    float4 s0 = *reinterpret_cast<const float4*>(st + s * 64 + (d8 & 63));
    float4 s1 = *reinterpret_cast<const float4*>(st + s * 64 + (d8 & 63) + 4);
    float cc[8] = {c0.x, c0.y, c0.z, c0.w, c1.x, c1.y, c1.z, c1.w};
    float ss[8] = {s0.x, s0.y, s0.z, s0.w, s1.x, s1.y, s1.z, s1.w};
    float sgn = (d8 < 64) ? -1.0f : 1.0f;
    float sc = (slot < 4) ? QSCALE : 1.0f;
    unsigned short o[8];
#pragma unroll
    for (int i = 0; i < 8; ++i) {
      float x = bf16_f32((unsigned short)x8[i]);
      float r = bf16_f32((unsigned short)r8[i]) * sgn;
      o[i] = f32_bf16((x * cc[i] + r * ss[i]) * sc);
    }
    unsigned short* dst = (slot < 4)
        ? Q + ((size_t)(g * 4 + slot) * SEQ + s) * HD + d8
        : Kh + ((size_t)g * SEQ + s) * HD + d8;
    *reinterpret_cast<uint4*>(dst) = *reinterpret_cast<uint4*>(o);
  } else {
    int t2 = (b - 5120) * 256 + threadIdx.x;
    int d = t2 & 127;
    int rest = t2 >> 7;
    int g = rest & 7;
    int s0 = (rest >> 3) * 8;
    const unsigned short* src = qkvb + (size_t)s0 * QKV_OUT + g * 768 + 640 + d;
    unsigned short o[8];
#pragma unroll
    for (int i = 0; i < 8; ++i) o[i] = src[(size_t)i * QKV_OUT];
    *reinterpret_cast<uint4*>(&Vt[((size_t)g * HD + d) * SEQ + s0]) =
        *reinterpret_cast<uint4*>(o);
  }
}

// next valid blocksparse j >= x for this qb (uniform across block), -1 if none.
__device__ inline int nextj(int x, int qb) {
  if (x > qb) return -1;
  if (qb - x < 16) return x;
  int v = (x & ~7) + 7;
  int w = qb - 15;
  return v < w ? v : w;
}

// ---------------- blocksparse flash attention (unchanged, R8-passing) --------
__global__ __launch_bounds__(256, 2) void attn32(const unsigned short* __restrict__ Q,
                                                 const unsigned short* __restrict__ Kh,
                                                 const unsigned short* __restrict__ Vt,
                                                 unsigned short* __restrict__ ctx) {
  const int g = blockIdx.x;
  const int y = (int)gridDim.y - 1 - (int)blockIdx.y;
  const int qb = y >> 1, half = y & 1;
  const int Q0 = y * 32;
  const int tid = threadIdx.x;
  const int wave = tid >> 6;
  const int h = g * 4 + wave;
  const int lane = tid & 63;
  const int l31 = lane & 31, hi = lane >> 5;

  __shared__ __align__(16) char Lds[65536];

  auto stage = [&](int bufb, int j) {
#pragma unroll
    for (int i = 0; i < 4; ++i) {
      int row = i * 16 + (tid >> 4);
      const unsigned short* src =
          Kh + ((size_t)(g * SEQ + j * 64 + row)) * HD + ((tid & 15) ^ (row & 15)) * 8;
      __builtin_amdgcn_global_load_lds(
          (const __attribute__((address_space(1))) unsigned int*)src,
          (__attribute__((address_space(3))) unsigned int*)(Lds + bufb + i * 4096 + (tid >> 6) * 1024),
          16, 0, 0);
    }
#pragma unroll
    for (int i = 0; i < 4; ++i) {
      int row = i * 32 + (tid >> 3);
      const unsigned short* src =
          Vt + ((size_t)(g * HD + row)) * SEQ + j * 64 + ((tid & 7) ^ (row & 7)) * 8;
      __builtin_amdgcn_global_load_lds(
          (const __attribute__((address_space(1))) unsigned int*)src,
          (__attribute__((address_space(3))) unsigned int*)(Lds + bufb + 16384 + i * 4096 + (tid >> 6) * 1024),
          16, 0, 0);
    }
  };

  bf16x8 qf[8];
  const unsigned short* qbase = Q + ((size_t)h * SEQ + Q0 + l31) * HD;
#pragma unroll
  for (int kk = 0; kk < 8; ++kk)
    qf[kk] = *reinterpret_cast<const bf16x8*>(qbase + kk * 16 + hi * 8);

  f32x16 ot[4] = {};
  float mrow = -1e30f, lsum = 0.f;

  const int kswz = l31 & 15;
  const int vswz = l31 & 7;

  int j = nextj(0, qb);
  int cur = 0;
  stage(0, j);
  asm volatile("s_waitcnt vmcnt(0)" ::: "memory");
  __builtin_amdgcn_sched_barrier(0);
  __builtin_amdgcn_s_barrier();
  __builtin_amdgcn_sched_barrier(0);

  while (true) {
    const int jn = (j < qb) ? nextj(j + 1, qb) : -1;
    if (jn >= 0) stage(cur ^ 32768, jn);

    const char* kb = Lds + cur;
    const char* vb = Lds + cur + 16384;
    const bool diag = (j == qb);
    const bool short_blk = diag && (half == 0);

    f32x16 st[2] = {};
    __builtin_amdgcn_s_setprio(1);
#pragma unroll
    for (int kk = 0; kk < 8; ++kk) {
      bf16x8 k0 = *reinterpret_cast<const bf16x8*>(
          kb + (size_t)l31 * 256 + (((2 * kk + hi) ^ kswz) * 16));
      st[0] = __builtin_amdgcn_mfma_f32_32x32x16_bf16(k0, qf[kk], st[0], 0, 0, 0);
      if (!short_blk) {
        bf16x8 k1 = *reinterpret_cast<const bf16x8*>(
            kb + (size_t)(32 + l31) * 256 + (((2 * kk + hi) ^ kswz) * 16));
        st[1] = __builtin_amdgcn_mfma_f32_32x32x16_bf16(k1, qf[kk], st[1], 0, 0, 0);
      }
    }
    __builtin_amdgcn_s_setprio(0);

    if (diag) {
      int qrel = half * 32 + l31;
#pragma unroll
      for (int kt = 0; kt < 2; ++kt)
#pragma unroll
        for (int r = 0; r < 16; ++r) {
          int krel = kt * 32 + (r & 3) + 8 * (r >> 2) + 4 * hi;
          if (krel > qrel) st[kt][r] = -1e30f;
        }
    }

    float t16[16];
#pragma unroll
    for (int r = 0; r < 16; ++r) t16[r] = fmaxf(st[0][r], st[1][r]);
#pragma unroll
    for (int sft = 8; sft >= 1; sft >>= 1)
#pragma unroll
      for (int r = 0; r < sft; ++r) t16[r] = fmaxf(t16[r], t16[r + sft]);
    float vm = xmax32(t16[0]);

    if (!__all(vm - mrow <= 8.0f)) {
      float nm = fmaxf(mrow, vm);
      float corr = __builtin_amdgcn_exp2f(mrow - nm);
      lsum *= corr;
#pragma unroll
      for (int dt = 0; dt < 4; ++dt)
#pragma unroll
        for (int r = 0; r < 16; ++r) ot[dt][r] *= corr;
      mrow = nm;
    }

    float s4[4] = {0.f, 0.f, 0.f, 0.f};
#pragma unroll
    for (int kt = 0; kt < 2; ++kt)
#pragma unroll
      for (int r = 0; r < 16; ++r) {
        float p = __builtin_amdgcn_exp2f(st[kt][r] - mrow);
        st[kt][r] = p;
        s4[r & 3] += p;
      }
    lsum += xadd32((s4[0] + s4[1]) + (s4[2] + s4[3]));

    bf16x8 pb[4];
#pragma unroll
    for (int s = 0; s < 4; ++s) {
      int kt = s >> 1, g0 = (s & 1) * 2, g1 = g0 + 1;
      unsigned int a0 = pk(st[kt][4 * g0 + 0], st[kt][4 * g0 + 1]);
      unsigned int a1 = pk(st[kt][4 * g0 + 2], st[kt][4 * g0 + 3]);
      unsigned int b0 = pk(st[kt][4 * g1 + 0], st[kt][4 * g1 + 1]);
      unsigned int b1 = pk(st[kt][4 * g1 + 2], st[kt][4 * g1 + 3]);
      pswap(a0, b0);
      pswap(a1, b1);
      union { unsigned int u[4]; bf16x8 v; } t;
      t.u[0] = a0; t.u[1] = a1; t.u[2] = b0; t.u[3] = b1;
      pb[s] = t.v;
    }

    const int smax = short_blk ? 2 : 4;
    __builtin_amdgcn_s_setprio(1);
#pragma unroll
    for (int dt = 0; dt < 4; ++dt) {
      const char* vrow = vb + (size_t)(dt * 32 + l31) * 128;
#pragma unroll
      for (int s = 0; s < 4; ++s)
        if (s < smax)
          ot[dt] = __builtin_amdgcn_mfma_f32_32x32x16_bf16(
              *reinterpret_cast<const bf16x8*>(vrow + (((2 * s + hi) ^ vswz) * 16)),
              pb[s], ot[dt], 0, 0, 0);
    }
    __builtin_amdgcn_s_setprio(0);

    if (jn < 0) break;
    asm volatile("s_waitcnt vmcnt(0)" ::: "memory");
    __builtin_amdgcn_sched_barrier(0);
    __builtin_amdgcn_s_barrier();
    __builtin_amdgcn_sched_barrier(0);
    j = jn;
    cur ^= 32768;
  }

  __syncthreads();
  char* W = Lds + wave * 8192;
  float inv = 1.0f / lsum;
  const int swz = (l31 & 7) << 4;
#pragma unroll
  for (int dt = 0; dt < 4; ++dt)
#pragma unroll
    for (int gg = 0; gg < 4; ++gg) {
      unsigned int u0 = pk(ot[dt][4 * gg + 0] * inv, ot[dt][4 * gg + 1] * inv);
      unsigned int u1 = pk(ot[dt][4 * gg + 2] * inv, ot[dt][4 * gg + 3] * inv);
      int off = (dt * 64 + gg * 16 + hi * 8) ^ swz;
      *reinterpret_cast<uint2*>(W + l31 * 256 + off) = make_uint2(u0, u1);
    }
#pragma unroll
  for (int i = 0; i < 8; ++i) {
    int row = lane >> 1;
    int t = (lane & 1) * 8 + i;
    bf16x8 vv = *reinterpret_cast<const bf16x8*>(
        W + row * 256 + ((t * 16) ^ ((row & 7) << 4)));
    *reinterpret_cast<bf16x8*>(&ctx[(size_t)(Q0 + row) * HIDDEN + h * HD + t * 8]) = vv;
  }
}

extern "C" void kernel_launch(void* const* d_in, const int* in_sizes, int n_in,
                              void* d_out, int out_size, void* d_ws, size_t ws_size,
                              hipStream_t stream) {
  const float* hidden  = (const float*)d_in[0];
  const float* w_qkv   = (const float*)d_in[1];
  const float* b_qkv   = (const float*)d_in[2];
  const float* w_dense = (const float*)d_in[3];
  const float* b_dense = (const float*)d_in[4];
  float* out = (float*)d_out;

  char* p = (char*)d_ws;
  unsigned short* hid_bf  = (unsigned short*)p; p += (size_t)SEQ * HIDDEN * 2;
  unsigned short* wqkv_bf = (unsigned short*)p; p += (size_t)QKV_OUT * HIDDEN * 2;
  unsigned short* wd_bf   = (unsigned short*)p; p += (size_t)HIDDEN * HIDDEN * 2;
  unsigned short* qkvb    = (unsigned short*)p; p += (size_t)SEQ * QKV_OUT * 2;
  unsigned short* Qb      = (unsigned short*)p; p += (size_t)NH * SEQ * HD * 2;
  unsigned short* Kb      = (unsigned short*)p; p += (size_t)NKV * SEQ * HD * 2;
  unsigned short* Vt      = (unsigned short*)p; p += (size_t)NKV * HD * SEQ * 2;
  float* ct               = (float*)p;          p += (size_t)SEQ * 64 * 4;
  float* st               = (float*)p;          p += (size_t)SEQ * 64 * 4;
  unsigned short* ctx = hid_bf;  // hidden_bf16 dead after QKV GEMM

  // all fp32->bf16 casts + rope tables in ONE launch
  const int prep_blocks = (int)((N1 + N2 + N4 + N3 + 255) / 256);
  prep<<<prep_blocks, 256, 0, stream>>>(hidden, hid_bf, w_qkv, wqkv_bf,
                                        w_dense, wd_bf, ct, st);

  // QKV: BM=256 x BN=192 -> 8 x 32 = 256 blocks (100% CU occupancy).
  gemmG<256, 192, 4, 8, true>
      <<<dim3((SEQ / 256) * (QKV_OUT / 192)), 512, 0, stream>>>(
          hid_bf, wqkv_bf, b_qkv, qkvb, SEQ, QKV_OUT, HIDDEN);
  rope_split<<<5120 + 1024, 256, 0, stream>>>(qkvb, ct, st, Qb, Kb, Vt);
  attn32<<<dim3(NKV, SEQ / 32), 256, 0, stream>>>(Qb, Kb, Vt, ctx);
  // dense: BM=128 x BN=256 -> 16 x 16 = 256 blocks (R11-identical indexing).
  gemmG<128, 256, 8, 4, false>
      <<<dim3((SEQ / 128) * (HIDDEN / 256)), 512, 0, stream>>>(
          ctx, wd_bf, b_dense, out, SEQ, HIDDEN, HIDDEN);
}

// Round 17
// 269.308 us; speedup vs baseline: 1.3018x; 1.0201x over previous
//
#include <hip/hip_runtime.h>
#include <hip/hip_bf16.h>

#define SEQ 2048
#define HIDDEN 4096
#define NH 32
#define NKV 8
#define HD 128
#define QKV_OUT 6144   // (32 + 2*8) * 128
// Q is pre-scaled by SM_SCALE*log2(e) so softmax uses exp2 directly.
#define QSCALE (0.0078125f * 1.4426950408889634f)

typedef __attribute__((ext_vector_type(8))) short bf16x8;
typedef __attribute__((ext_vector_type(4))) float f32x4;
typedef __attribute__((ext_vector_type(16))) float f32x16;

__device__ inline unsigned short f32_bf16(float f) {
  union { float f; unsigned int u; } v; v.f = f;
  unsigned int r = v.u + 0x7FFFu + ((v.u >> 16) & 1u);
  return (unsigned short)(r >> 16);
}
__device__ inline float bf16_f32(unsigned short u) {
  union { unsigned int u; float f; } v; v.u = (unsigned int)u << 16;
  return v.f;
}
__device__ inline unsigned int pk(float a, float b) {
  union { __hip_bfloat162 h; unsigned int u; } t;
  t.h = __float22bfloat162_rn(make_float2(a, b));
  return t.u;
}
__device__ inline void pswap(unsigned int &a, unsigned int &b) {
  auto r = __builtin_amdgcn_permlane32_swap((int)a, (int)b, false, false);
  a = (unsigned int)r[0]; b = (unsigned int)r[1];
}
__device__ inline float xmax32(float v) {
  int x = __builtin_bit_cast(int, v);
  auto r = __builtin_amdgcn_permlane32_swap(x, x, false, false);
  return fmaxf(__builtin_bit_cast(float, (int)r[0]), __builtin_bit_cast(float, (int)r[1]));
}
__device__ inline float xadd32(float v) {
  int x = __builtin_bit_cast(int, v);
  auto r = __builtin_amdgcn_permlane32_swap(x, x, false, false);
  return __builtin_bit_cast(float, (int)r[0]) + __builtin_bit_cast(float, (int)r[1]);
}

__device__ inline void cast8(const float* __restrict__ in, unsigned short* __restrict__ out) {
  float4 a = *reinterpret_cast<const float4*>(in);
  float4 b = *reinterpret_cast<const float4*>(in + 4);
  unsigned short t[8];
  t[0] = f32_bf16(a.x); t[1] = f32_bf16(a.y); t[2] = f32_bf16(a.z); t[3] = f32_bf16(a.w);
  t[4] = f32_bf16(b.x); t[5] = f32_bf16(b.y); t[6] = f32_bf16(b.z); t[7] = f32_bf16(b.w);
  *reinterpret_cast<uint4*>(out) = *reinterpret_cast<uint4*>(t);
}

// ------- prep: conv(hidden) + conv(w_qkv) + conv(w_dense) + RoPE tables ------
#define N1 ((size_t)SEQ * HIDDEN / 8)        // 1,048,576
#define N2 ((size_t)QKV_OUT * HIDDEN / 8)    // 3,145,728
#define N4 ((size_t)HIDDEN * HIDDEN / 8)     // 2,097,152
#define N3 ((size_t)SEQ * 64)                // 131,072
__global__ __launch_bounds__(256) void prep(const float* __restrict__ hid,
                                            unsigned short* __restrict__ hid_bf,
                                            const float* __restrict__ wq,
                                            unsigned short* __restrict__ wq_bf,
                                            const float* __restrict__ wd,
                                            unsigned short* __restrict__ wd_bf,
                                            float* __restrict__ ct,
                                            float* __restrict__ st) {
  size_t i = (size_t)blockIdx.x * 256 + threadIdx.x;
  if (i < N1) {
    cast8(hid + i * 8, hid_bf + i * 8);
  } else if (i < N1 + N2) {
    size_t j = (i - N1) * 8;
    cast8(wq + j, wq_bf + j);
  } else if (i < N1 + N2 + N4) {
    size_t j = (i - N1 - N2) * 8;
    cast8(wd + j, wd_bf + j);
  } else {
    size_t j = i - N1 - N2 - N4;  // < N3
    int s = (int)(j >> 6), d = (int)(j & 63);
    float inv = powf(1.0e6f, -(float)d * (1.0f / 64.0f));
    float f = (float)s * inv;
    ct[j] = cosf(f);
    st[j] = sinf(f);
  }
}

// ---------------- generalized 4-phase/1-barrier GEMM (gemm9 family) ----------
// C[M,N] = A[M,K]*B[N,K]^T + bias. 512 threads = 8 waves (2M x 4N).
// R17 change vs R16 (load-age deepening): ALL stages for tile t+1 issue at
// q0 (A halves) and q1 (all B) of tile t, none at q2/q3. At tile t's q0 wait,
// the youngest drained load (q1(t-1) B) is ~3 quadrants (~450-750 cyc) old —
// vs 1 quadrant in R16 — so the barrier no longer eats exposed L2/HBM latency.
// vmcnt counts only t's own q0 stages (2*La). Buffer/race pattern unchanged.
// Zero-conflict swizzle: source chunk ^= row&7, read col ^= (lrow&7)<<4.
template <int BM, int BN, int CR, int CC, bool OBF>
__global__ __launch_bounds__(512, 2) void gemmG(const unsigned short* __restrict__ A,
                                                const unsigned short* __restrict__ B,
                                                const float* __restrict__ bias,
                                                void* __restrict__ Cp,
                                                int M, int N, int K) {
  constexpr int MQ   = BM / 64;         // A frags per (wave, mh-half)
  constexpr int NREP = BN / 64;         // B frags per wave (wave cols = 16*NREP)
  constexpr int NB0  = (NREP + 1) / 2;  // frags computed in first n-phase
  constexpr int La   = BM / 128;        // A gloads per wave per half
  constexpr int NB   = BN / 64;         // B gloads per wave per tile
  constexpr int AH   = BM * 64;         // bytes per A-half section
  constexpr int SB   = 2 * AH + BN * 128;
  __shared__ __align__(16) char Lds[SB * 2];

  const int tid = threadIdx.x;
  const int wave = tid >> 6, lane = tid & 63;
  const int wr = wave >> 2, wc = wave & 3;
  const int lrow = lane & 15, lgrp = lane >> 4;

  // 2D XCD chunk
  const int ntx = N / BN;
  const int wg0 = blockIdx.x;
  const int xcd = wg0 & 7, w = wg0 >> 3;
  const int cpb = ntx / CC;
  const int band = xcd / cpb, colc = xcd % cpb;
  const int bm = (band * CR + w / CC) * BM;
  const int bn = (colc * CC + w % CC) * BN;

  const int r8 = lane >> 3;
  const int scol = ((lane & 7) ^ r8) * 8;  // pre-swizzled source chunk

  const unsigned short* gA[2][La]; int lA[2][La];
#pragma unroll
  for (int u = 0; u < 2; ++u)
#pragma unroll
    for (int j = 0; j < La; ++j) {
      int row = bm + u * (BM / 2) + wave * (BM / 16) + j * 8 + r8;
      gA[u][j] = A + (size_t)row * K + scol;
      lA[u][j] = u * AH + (wave * (BM / 16) + j * 8) * 128;
    }
  const unsigned short* gB[NB]; int lB[NB];
#pragma unroll
  for (int j = 0; j < NB; ++j) {
    int row = bn + wave * (BN / 8) + j * 8 + r8;
    gB[j] = B + (size_t)row * K + scol;
    lB[j] = 2 * AH + (wave * (BN / 8) + j * 8) * 128;
  }

  auto stageA2 = [&](int bufb, int k0) {  // both A halves (2*La loads)
#pragma unroll
    for (int u = 0; u < 2; ++u)
#pragma unroll
      for (int j = 0; j < La; ++j)
        __builtin_amdgcn_global_load_lds(
            (const __attribute__((address_space(1))) unsigned int*)(gA[u][j] + k0),
            (__attribute__((address_space(3))) unsigned int*)(Lds + bufb + lA[u][j]), 16, 0, 0);
  };
  auto stageB = [&](int bufb, int k0) {   // all B loads (NB)
#pragma unroll
    for (int j = 0; j < NB; ++j)
      __builtin_amdgcn_global_load_lds(
          (const __attribute__((address_space(1))) unsigned int*)(gB[j] + k0),
          (__attribute__((address_space(3))) unsigned int*)(Lds + bufb + lB[j]), 16, 0, 0);
  };

  const int rsw = (lrow & 7) << 4;
  auto aoff = [&](int mh, int m, int ks) {
    int r = mh * (BM / 4) + m * 16 + lrow;
    return wr * AH + r * 128 + ((ks * 64 + lgrp * 16) ^ rsw);
  };
  auto boff = [&](int nf, int ks) {
    int r = wc * (BN / 4) + nf * 16 + lrow;
    return 2 * AH + r * 128 + ((ks * 64 + lgrp * 16) ^ rsw);
  };

  f32x4 acc[2 * MQ][NREP] = {};
  bf16x8 af[MQ][2], bf[NREP][2];

  const int nt = K / 64;
  stageA2(0, 0);
  stageB(0, 0);

  for (int t = 0; t < nt; ++t) {
    const int cur = (t & 1) ? SB : 0;
    const int nxt = cur ^ SB;
    const bool pf = (t + 1) < nt;
    const int k1 = (t + 1) * 64;
    const char* base = Lds + cur;

    // ---- q0: stage A(t+1); the ONE counted wait + barrier per tile ----
    if (pf) {
      stageA2(nxt, k1);
      if constexpr (La == 2) asm volatile("s_waitcnt vmcnt(4)" ::: "memory");
      else                   asm volatile("s_waitcnt vmcnt(2)" ::: "memory");
    } else {
      asm volatile("s_waitcnt vmcnt(0)" ::: "memory");
    }
    __builtin_amdgcn_sched_barrier(0);
    __builtin_amdgcn_s_barrier();
    __builtin_amdgcn_sched_barrier(0);
#pragma unroll
    for (int m = 0; m < MQ; ++m)
#pragma unroll
      for (int ks = 0; ks < 2; ++ks)
        af[m][ks] = *reinterpret_cast<const bf16x8*>(base + aoff(0, m, ks));
#pragma unroll
    for (int nf = 0; nf < NB0; ++nf)
#pragma unroll
      for (int ks = 0; ks < 2; ++ks)
        bf[nf][ks] = *reinterpret_cast<const bf16x8*>(base + boff(nf, ks));
    __builtin_amdgcn_s_setprio(1);
#pragma unroll
    for (int m = 0; m < MQ; ++m)
#pragma unroll
      for (int nf = 0; nf < NB0; ++nf)
#pragma unroll
        for (int ks = 0; ks < 2; ++ks)
          acc[m][nf] = __builtin_amdgcn_mfma_f32_16x16x32_bf16(af[m][ks], bf[nf][ks], acc[m][nf], 0, 0, 0);
    __builtin_amdgcn_s_setprio(0);

    // ---- q1: stage all B(t+1) ----
    if (pf) stageB(nxt, k1);
#pragma unroll
    for (int nf = NB0; nf < NREP; ++nf)
#pragma unroll
      for (int ks = 0; ks < 2; ++ks)
        bf[nf][ks] = *reinterpret_cast<const bf16x8*>(base + boff(nf, ks));
    __builtin_amdgcn_s_setprio(1);
#pragma unroll
    for (int m = 0; m < MQ; ++m)
#pragma unroll
      for (int nf = NB0; nf < NREP; ++nf)
#pragma unroll
        for (int ks = 0; ks < 2; ++ks)
          acc[m][nf] = __builtin_amdgcn_mfma_f32_16x16x32_bf16(af[m][ks], bf[nf][ks], acc[m][nf], 0, 0, 0);
    __builtin_amdgcn_s_setprio(0);

    // ---- q2 ----
#pragma unroll
    for (int m = 0; m < MQ; ++m)
#pragma unroll
      for (int ks = 0; ks < 2; ++ks)
        af[m][ks] = *reinterpret_cast<const bf16x8*>(base + aoff(1, m, ks));
    __builtin_amdgcn_s_setprio(1);
#pragma unroll
    for (int m = 0; m < MQ; ++m)
#pragma unroll
      for (int nf = 0; nf < NB0; ++nf)
#pragma unroll
        for (int ks = 0; ks < 2; ++ks)
          acc[MQ + m][nf] = __builtin_amdgcn_mfma_f32_16x16x32_bf16(af[m][ks], bf[nf][ks], acc[MQ + m][nf], 0, 0, 0);
    __builtin_amdgcn_s_setprio(0);

    // ---- q3 ----
    __builtin_amdgcn_s_setprio(1);
#pragma unroll
    for (int m = 0; m < MQ; ++m)
#pragma unroll
      for (int nf = NB0; nf < NREP; ++nf)
#pragma unroll
        for (int ks = 0; ks < 2; ++ks)
          acc[MQ + m][nf] = __builtin_amdgcn_mfma_f32_16x16x32_bf16(af[m][ks], bf[nf][ks], acc[MQ + m][nf], 0, 0, 0);
    __builtin_amdgcn_s_setprio(0);
  }

  // epilogue: bias + store
#pragma unroll
  for (int ni = 0; ni < NREP; ++ni) {
    int col = bn + wc * (BN / 4) + ni * 16 + lrow;
    float bv = bias[col];
#pragma unroll
    for (int mi = 0; mi < 2 * MQ; ++mi)
#pragma unroll
      for (int r = 0; r < 4; ++r) {
        int row = bm + wr * (BM / 2) + mi * 16 + lgrp * 4 + r;
        if constexpr (OBF)
          ((unsigned short*)Cp)[(size_t)row * N + col] = f32_bf16(acc[mi][ni][r] + bv);
        else
          ((float*)Cp)[(size_t)row * N + col] = acc[mi][ni][r] + bv;
      }
  }
}

// ---------------- RoPE + split (bf16 qkv input), vectorized ------------------
__global__ __launch_bounds__(256) void rope_split(const unsigned short* __restrict__ qkvb,
                                                  const float* __restrict__ ct,
                                                  const float* __restrict__ st,
                                                  unsigned short* __restrict__ Q,
                                                  unsigned short* __restrict__ Kh,
                                                  unsigned short* __restrict__ Vt) {
  int b = blockIdx.x;
  if (b < 5120) {
    int t = b * 256 + threadIdx.x;
    int d8 = (t & 15) * 8;
    int q = t >> 4;
    int s = q / 40;
    int slotg = q - s * 40;
    int g = slotg / 5, slot = slotg - g * 5;
    const unsigned short* base = qkvb + (size_t)s * QKV_OUT + g * 768 + slot * 128;
    bf16x8 x8 = *reinterpret_cast<const bf16x8*>(base + d8);
    bf16x8 r8 = *reinterpret_cast<const bf16x8*>(base + (d8 ^ 64));
    float4 c0 = *reinterpret_cast<const float4*>(ct + s * 64 + (d8 & 63));
    float4 c1 = *reinterpret_cast<const float4*>(ct + s * 64 + (d8 & 63) + 4);
    float4 s0 = *reinterpret_cast<const float4*>(st + s * 64 + (d8 & 63));
    float4 s1 = *reinterpret_cast<const float4*>(st + s * 64 + (d8 & 63) + 4);
    float cc[8] = {c0.x, c0.y, c0.z, c0.w, c1.x, c1.y, c1.z, c1.w};
    float ss[8] = {s0.x, s0.y, s0.z, s0.w, s1.x, s1.y, s1.z, s1.w};
    float sgn = (d8 < 64) ? -1.0f : 1.0f;
    float sc = (slot < 4) ? QSCALE : 1.0f;
    unsigned short o[8];
#pragma unroll
    for (int i = 0; i < 8; ++i) {
      float x = bf16_f32((unsigned short)x8[i]);
      float r = bf16_f32((unsigned short)r8[i]) * sgn;
      o[i] = f32_bf16((x * cc[i] + r * ss[i]) * sc);
    }
    unsigned short* dst = (slot < 4)
        ? Q + ((size_t)(g * 4 + slot) * SEQ + s) * HD + d8
        : Kh + ((size_t)g * SEQ + s) * HD + d8;
    *reinterpret_cast<uint4*>(dst) = *reinterpret_cast<uint4*>(o);
  } else {
    int t2 = (b - 5120) * 256 + threadIdx.x;
    int d = t2 & 127;
    int rest = t2 >> 7;
    int g = rest & 7;
    int s0 = (rest >> 3) * 8;
    const unsigned short* src = qkvb + (size_t)s0 * QKV_OUT + g * 768 + 640 + d;
    unsigned short o[8];
#pragma unroll
    for (int i = 0; i < 8; ++i) o[i] = src[(size_t)i * QKV_OUT];
    *reinterpret_cast<uint4*>(&Vt[((size_t)g * HD + d) * SEQ + s0]) =
        *reinterpret_cast<uint4*>(o);
  }
}

// next valid blocksparse j >= x for this qb (uniform across block), -1 if none.
__device__ inline int nextj(int x, int qb) {
  if (x > qb) return -1;
  if (qb - x < 16) return x;
  int v = (x & ~7) + 7;
  int w = qb - 15;
  return v < w ? v : w;
}

// ---------------- blocksparse flash attention (unchanged, R8-passing) --------
__global__ __launch_bounds__(256, 2) void attn32(const unsigned short* __restrict__ Q,
                                                 const unsigned short* __restrict__ Kh,
                                                 const unsigned short* __restrict__ Vt,
                                                 unsigned short* __restrict__ ctx) {
  const int g = blockIdx.x;
  const int y = (int)gridDim.y - 1 - (int)blockIdx.y;
  const int qb = y >> 1, half = y & 1;
  const int Q0 = y * 32;
  const int tid = threadIdx.x;
  const int wave = tid >> 6;
  const int h = g * 4 + wave;
  const int lane = tid & 63;
  const int l31 = lane & 31, hi = lane >> 5;

  __shared__ __align__(16) char Lds[65536];

  auto stage = [&](int bufb, int j) {
#pragma unroll
    for (int i = 0; i < 4; ++i) {
      int row = i * 16 + (tid >> 4);
      const unsigned short* src =
          Kh + ((size_t)(g * SEQ + j * 64 + row)) * HD + ((tid & 15) ^ (row & 15)) * 8;
      __builtin_amdgcn_global_load_lds(
          (const __attribute__((address_space(1))) unsigned int*)src,
          (__attribute__((address_space(3))) unsigned int*)(Lds + bufb + i * 4096 + (tid >> 6) * 1024),
          16, 0, 0);
    }
#pragma unroll
    for (int i = 0; i < 4; ++i) {
      int row = i * 32 + (tid >> 3);
      const unsigned short* src =
          Vt + ((size_t)(g * HD + row)) * SEQ + j * 64 + ((tid & 7) ^ (row & 7)) * 8;
      __builtin_amdgcn_global_load_lds(
          (const __attribute__((address_space(1))) unsigned int*)src,
          (__attribute__((address_space(3))) unsigned int*)(Lds + bufb + 16384 + i * 4096 + (tid >> 6) * 1024),
          16, 0, 0);
    }
  };

  bf16x8 qf[8];
  const unsigned short* qbase = Q + ((size_t)h * SEQ + Q0 + l31) * HD;
#pragma unroll
  for (int kk = 0; kk < 8; ++kk)
    qf[kk] = *reinterpret_cast<const bf16x8*>(qbase + kk * 16 + hi * 8);

  f32x16 ot[4] = {};
  float mrow = -1e30f, lsum = 0.f;

  const int kswz = l31 & 15;
  const int vswz = l31 & 7;

  int j = nextj(0, qb);
  int cur = 0;
  stage(0, j);
  asm volatile("s_waitcnt vmcnt(0)" ::: "memory");
  __builtin_amdgcn_sched_barrier(0);
  __builtin_amdgcn_s_barrier();
  __builtin_amdgcn_sched_barrier(0);

  while (true) {
    const int jn = (j < qb) ? nextj(j + 1, qb) : -1;
    if (jn >= 0) stage(cur ^ 32768, jn);

    const char* kb = Lds + cur;
    const char* vb = Lds + cur + 16384;
    const bool diag = (j == qb);
    const bool short_blk = diag && (half == 0);

    f32x16 st[2] = {};
    __builtin_amdgcn_s_setprio(1);
#pragma unroll
    for (int kk = 0; kk < 8; ++kk) {
      bf16x8 k0 = *reinterpret_cast<const bf16x8*>(
          kb + (size_t)l31 * 256 + (((2 * kk + hi) ^ kswz) * 16));
      st[0] = __builtin_amdgcn_mfma_f32_32x32x16_bf16(k0, qf[kk], st[0], 0, 0, 0);
      if (!short_blk) {
        bf16x8 k1 = *reinterpret_cast<const bf16x8*>(
            kb + (size_t)(32 + l31) * 256 + (((2 * kk + hi) ^ kswz) * 16));
        st[1] = __builtin_amdgcn_mfma_f32_32x32x16_bf16(k1, qf[kk], st[1], 0, 0, 0);
      }
    }
    __builtin_amdgcn_s_setprio(0);

    if (diag) {
      int qrel = half * 32 + l31;
#pragma unroll
      for (int kt = 0; kt < 2; ++kt)
#pragma unroll
        for (int r = 0; r < 16; ++r) {
          int krel = kt * 32 + (r & 3) + 8 * (r >> 2) + 4 * hi;
          if (krel > qrel) st[kt][r] = -1e30f;
        }
    }

    float t16[16];
#pragma unroll
    for (int r = 0; r < 16; ++r) t16[r] = fmaxf(st[0][r], st[1][r]);
#pragma unroll
    for (int sft = 8; sft >= 1; sft >>= 1)
#pragma unroll
      for (int r = 0; r < sft; ++r) t16[r] = fmaxf(t16[r], t16[r + sft]);
    float vm = xmax32(t16[0]);

    if (!__all(vm - mrow <= 8.0f)) {
      float nm = fmaxf(mrow, vm);
      float corr = __builtin_amdgcn_exp2f(mrow - nm);
      lsum *= corr;
#pragma unroll
      for (int dt = 0; dt < 4; ++dt)
#pragma unroll
        for (int r = 0; r < 16; ++r) ot[dt][r] *= corr;
      mrow = nm;
    }

    float s4[4] = {0.f, 0.f, 0.f, 0.f};
#pragma unroll
    for (int kt = 0; kt < 2; ++kt)
#pragma unroll
      for (int r = 0; r < 16; ++r) {
        float p = __builtin_amdgcn_exp2f(st[kt][r] - mrow);
        st[kt][r] = p;
        s4[r & 3] += p;
      }
    lsum += xadd32((s4[0] + s4[1]) + (s4[2] + s4[3]));

    bf16x8 pb[4];
#pragma unroll
    for (int s = 0; s < 4; ++s) {
      int kt = s >> 1, g0 = (s & 1) * 2, g1 = g0 + 1;
      unsigned int a0 = pk(st[kt][4 * g0 + 0], st[kt][4 * g0 + 1]);
      unsigned int a1 = pk(st[kt][4 * g0 + 2], st[kt][4 * g0 + 3]);
      unsigned int b0 = pk(st[kt][4 * g1 + 0], st[kt][4 * g1 + 1]);
      unsigned int b1 = pk(st[kt][4 * g1 + 2], st[kt][4 * g1 + 3]);
      pswap(a0, b0);
      pswap(a1, b1);
      union { unsigned int u[4]; bf16x8 v; } t;
      t.u[0] = a0; t.u[1] = a1; t.u[2] = b0; t.u[3] = b1;
      pb[s] = t.v;
    }

    const int smax = short_blk ? 2 : 4;
    __builtin_amdgcn_s_setprio(1);
#pragma unroll
    for (int dt = 0; dt < 4; ++dt) {
      const char* vrow = vb + (size_t)(dt * 32 + l31) * 128;
#pragma unroll
      for (int s = 0; s < 4; ++s)
        if (s < smax)
          ot[dt] = __builtin_amdgcn_mfma_f32_32x32x16_bf16(
              *reinterpret_cast<const bf16x8*>(vrow + (((2 * s + hi) ^ vswz) * 16)),
              pb[s], ot[dt], 0, 0, 0);
    }
    __builtin_amdgcn_s_setprio(0);

    if (jn < 0) break;
    asm volatile("s_waitcnt vmcnt(0)" ::: "memory");
    __builtin_amdgcn_sched_barrier(0);
    __builtin_amdgcn_s_barrier();
    __builtin_amdgcn_sched_barrier(0);
    j = jn;
    cur ^= 32768;
  }

  __syncthreads();
  char* W = Lds + wave * 8192;
  float inv = 1.0f / lsum;
  const int swz = (l31 & 7) << 4;
#pragma unroll
  for (int dt = 0; dt < 4; ++dt)
#pragma unroll
    for (int gg = 0; gg < 4; ++gg) {
      unsigned int u0 = pk(ot[dt][4 * gg + 0] * inv, ot[dt][4 * gg + 1] * inv);
      unsigned int u1 = pk(ot[dt][4 * gg + 2] * inv, ot[dt][4 * gg + 3] * inv);
      int off = (dt * 64 + gg * 16 + hi * 8) ^ swz;
      *reinterpret_cast<uint2*>(W + l31 * 256 + off) = make_uint2(u0, u1);
    }
#pragma unroll
  for (int i = 0; i < 8; ++i) {
    int row = lane >> 1;
    int t = (lane & 1) * 8 + i;
    bf16x8 vv = *reinterpret_cast<const bf16x8*>(
        W + row * 256 + ((t * 16) ^ ((row & 7) << 4)));
    *reinterpret_cast<bf16x8*>(&ctx[(size_t)(Q0 + row) * HIDDEN + h * HD + t * 8]) = vv;
  }
}

extern "C" void kernel_launch(void* const* d_in, const int* in_sizes, int n_in,
                              void* d_out, int out_size, void* d_ws, size_t ws_size,
                              hipStream_t stream) {
  const float* hidden  = (const float*)d_in[0];
  const float* w_qkv   = (const float*)d_in[1];
  const float* b_qkv   = (const float*)d_in[2];
  const float* w_dense = (const float*)d_in[3];
  const float* b_dense = (const float*)d_in[4];
  float* out = (float*)d_out;

  char* p = (char*)d_ws;
  unsigned short* hid_bf  = (unsigned short*)p; p += (size_t)SEQ * HIDDEN * 2;
  unsigned short* wqkv_bf = (unsigned short*)p; p += (size_t)QKV_OUT * HIDDEN * 2;
  unsigned short* wd_bf   = (unsigned short*)p; p += (size_t)HIDDEN * HIDDEN * 2;
  unsigned short* qkvb    = (unsigned short*)p; p += (size_t)SEQ * QKV_OUT * 2;
  unsigned short* Qb      = (unsigned short*)p; p += (size_t)NH * SEQ * HD * 2;
  unsigned short* Kb      = (unsigned short*)p; p += (size_t)NKV * SEQ * HD * 2;
  unsigned short* Vt      = (unsigned short*)p; p += (size_t)NKV * HD * SEQ * 2;
  float* ct               = (float*)p;          p += (size_t)SEQ * 64 * 4;
  float* st               = (float*)p;          p += (size_t)SEQ * 64 * 4;
  unsigned short* ctx = hid_bf;  // hidden_bf16 dead after QKV GEMM

  const int prep_blocks = (int)((N1 + N2 + N4 + N3 + 255) / 256);
  prep<<<prep_blocks, 256, 0, stream>>>(hidden, hid_bf, w_qkv, wqkv_bf,
                                        w_dense, wd_bf, ct, st);

  // QKV: BM=256 x BN=192 -> 8 x 32 = 256 blocks (100% CU occupancy).
  gemmG<256, 192, 4, 8, true>
      <<<dim3((SEQ / 256) * (QKV_OUT / 192)), 512, 0, stream>>>(
          hid_bf, wqkv_bf, b_qkv, qkvb, SEQ, QKV_OUT, HIDDEN);
  rope_split<<<5120 + 1024, 256, 0, stream>>>(qkvb, ct, st, Qb, Kb, Vt);
  attn32<<<dim3(NKV, SEQ / 32), 256, 0, stream>>>(Qb, Kb, Vt, ctx);
  // dense: BM=128 x BN=256 -> 16 x 16 = 256 blocks.
  gemmG<128, 256, 8, 4, false>
      <<<dim3((SEQ / 128) * (HIDDEN / 256)), 512, 0, stream>>>(
          ctx, wd_bf, b_dense, out, SEQ, HIDDEN, HIDDEN);
}

// Round 18
// 267.047 us; speedup vs baseline: 1.3129x; 1.0085x over previous
//
#include <hip/hip_runtime.h>
#include <hip/hip_bf16.h>

#define SEQ 2048
#define HIDDEN 4096
#define NH 32
#define NKV 8
#define HD 128
#define QKV_OUT 6144   // (32 + 2*8) * 128
// Q is pre-scaled by SM_SCALE*log2(e) so softmax uses exp2 directly.
#define QSCALE (0.0078125f * 1.4426950408889634f)

typedef __attribute__((ext_vector_type(8))) short bf16x8;
typedef __attribute__((ext_vector_type(4))) float f32x4;
typedef __attribute__((ext_vector_type(16))) float f32x16;

__device__ inline unsigned short f32_bf16(float f) {
  union { float f; unsigned int u; } v; v.f = f;
  unsigned int r = v.u + 0x7FFFu + ((v.u >> 16) & 1u);
  return (unsigned short)(r >> 16);
}
__device__ inline float bf16_f32(unsigned short u) {
  union { unsigned int u; float f; } v; v.u = (unsigned int)u << 16;
  return v.f;
}
__device__ inline unsigned int pk(float a, float b) {
  union { __hip_bfloat162 h; unsigned int u; } t;
  t.h = __float22bfloat162_rn(make_float2(a, b));
  return t.u;
}
__device__ inline void pswap(unsigned int &a, unsigned int &b) {
  auto r = __builtin_amdgcn_permlane32_swap((int)a, (int)b, false, false);
  a = (unsigned int)r[0]; b = (unsigned int)r[1];
}
__device__ inline float xmax32(float v) {
  int x = __builtin_bit_cast(int, v);
  auto r = __builtin_amdgcn_permlane32_swap(x, x, false, false);
  return fmaxf(__builtin_bit_cast(float, (int)r[0]), __builtin_bit_cast(float, (int)r[1]));
}
__device__ inline float xadd32(float v) {
  int x = __builtin_bit_cast(int, v);
  auto r = __builtin_amdgcn_permlane32_swap(x, x, false, false);
  return __builtin_bit_cast(float, (int)r[0]) + __builtin_bit_cast(float, (int)r[1]);
}

__device__ inline void cast8(const float* __restrict__ in, unsigned short* __restrict__ out) {
  float4 a = *reinterpret_cast<const float4*>(in);
  float4 b = *reinterpret_cast<const float4*>(in + 4);
  unsigned short t[8];
  t[0] = f32_bf16(a.x); t[1] = f32_bf16(a.y); t[2] = f32_bf16(a.z); t[3] = f32_bf16(a.w);
  t[4] = f32_bf16(b.x); t[5] = f32_bf16(b.y); t[6] = f32_bf16(b.z); t[7] = f32_bf16(b.w);
  *reinterpret_cast<uint4*>(out) = *reinterpret_cast<uint4*>(t);
}

// ------- prep: conv(hidden) + conv(w_qkv) + conv(w_dense) + RoPE tables ------
#define N1 ((size_t)SEQ * HIDDEN / 8)
#define N2 ((size_t)QKV_OUT * HIDDEN / 8)
#define N4 ((size_t)HIDDEN * HIDDEN / 8)
#define N3 ((size_t)SEQ * 64)
__global__ __launch_bounds__(256) void prep(const float* __restrict__ hid,
                                            unsigned short* __restrict__ hid_bf,
                                            const float* __restrict__ wq,
                                            unsigned short* __restrict__ wq_bf,
                                            const float* __restrict__ wd,
                                            unsigned short* __restrict__ wd_bf,
                                            float* __restrict__ ct,
                                            float* __restrict__ st) {
  size_t i = (size_t)blockIdx.x * 256 + threadIdx.x;
  if (i < N1) {
    cast8(hid + i * 8, hid_bf + i * 8);
  } else if (i < N1 + N2) {
    size_t j = (i - N1) * 8;
    cast8(wq + j, wq_bf + j);
  } else if (i < N1 + N2 + N4) {
    size_t j = (i - N1 - N2) * 8;
    cast8(wd + j, wd_bf + j);
  } else {
    size_t j = i - N1 - N2 - N4;
    int s = (int)(j >> 6), d = (int)(j & 63);
    float inv = powf(1.0e6f, -(float)d * (1.0f / 64.0f));
    float f = (float)s * inv;
    ct[j] = cosf(f);
    st[j] = sinf(f);
  }
}

// ---------------- generalized 4-phase/1-barrier GEMM ------------------------
// 512 threads = 8 waves arranged RW rows x (8/RW) cols. NBUF LDS buffers:
// NBUF=2: R17 schedule (stage t+1 at q0/q1, youngest drained load 3 quadrants
// old). NBUF=3: stage t+2 (A after q0's barrier, B at q1) -> drained loads are
// 2 FULL TILES old; race-free since every wave finishes reading buf(t-1)
// (= buf(t+2) mod 3) before its barrier(t), and DMA issues after that barrier.
// Zero-conflict swizzle: source chunk ^= row&7, read col ^= (lrow&7)<<4.
template <int BM, int BN, int RW, int NBUF, int CR, int CC, bool OBF>
__global__ __launch_bounds__(512, 2) void gemmG(const unsigned short* __restrict__ A,
                                                const unsigned short* __restrict__ B,
                                                const float* __restrict__ bias,
                                                void* __restrict__ Cp,
                                                int M, int N, int K) {
  constexpr int CW   = 8 / RW;            // wave cols
  constexpr int MQ   = BM / (32 * RW);    // A frags per (wave, mh-half)
  constexpr int NREP = BN / (16 * CW);    // B frags per wave
  constexpr int NB0  = (NREP + 1) / 2;    // frags in first n-phase
  constexpr int La   = BM / 128;          // A gloads per wave per half
  constexpr int NB   = BN / 64;           // B gloads per wave per tile
  constexpr int AH   = BM * 64;           // bytes per A-half section
  constexpr int SB   = 2 * AH + BN * 128;
  __shared__ __align__(16) char Lds[SB * NBUF];

  const int tid = threadIdx.x;
  const int wave = tid >> 6, lane = tid & 63;
  const int wr = wave / CW, wc = wave % CW;
  const int lrow = lane & 15, lgrp = lane >> 4;

  // 2D XCD chunk
  const int ntx = N / BN;
  const int wg0 = blockIdx.x;
  const int xcd = wg0 & 7, w = wg0 >> 3;
  const int cpb = ntx / CC;
  const int band = xcd / cpb, colc = xcd % cpb;
  const int bm = (band * CR + w / CC) * BM;
  const int bn = (colc * CC + w % CC) * BN;

  const int r8 = lane >> 3;
  const int scol = ((lane & 7) ^ r8) * 8;  // pre-swizzled source chunk

  const unsigned short* gA[2][La]; int lA[2][La];
#pragma unroll
  for (int u = 0; u < 2; ++u)
#pragma unroll
    for (int j = 0; j < La; ++j) {
      int row = bm + u * (BM / 2) + wave * (BM / 16) + j * 8 + r8;
      gA[u][j] = A + (size_t)row * K + scol;
      lA[u][j] = u * AH + (wave * (BM / 16) + j * 8) * 128;
    }
  const unsigned short* gB[NB]; int lB[NB];
#pragma unroll
  for (int j = 0; j < NB; ++j) {
    int row = bn + wave * (BN / 8) + j * 8 + r8;
    gB[j] = B + (size_t)row * K + scol;
    lB[j] = 2 * AH + (wave * (BN / 8) + j * 8) * 128;
  }

  auto stageA2 = [&](int bufb, int k0) {
#pragma unroll
    for (int u = 0; u < 2; ++u)
#pragma unroll
      for (int j = 0; j < La; ++j)
        __builtin_amdgcn_global_load_lds(
            (const __attribute__((address_space(1))) unsigned int*)(gA[u][j] + k0),
            (__attribute__((address_space(3))) unsigned int*)(Lds + bufb + lA[u][j]), 16, 0, 0);
  };
  auto stageB = [&](int bufb, int k0) {
#pragma unroll
    for (int j = 0; j < NB; ++j)
      __builtin_amdgcn_global_load_lds(
          (const __attribute__((address_space(1))) unsigned int*)(gB[j] + k0),
          (__attribute__((address_space(3))) unsigned int*)(Lds + bufb + lB[j]), 16, 0, 0);
  };

  const int rsw = (lrow & 7) << 4;
  auto aoff = [&](int mh, int m, int ks) {
    int r = wr * (BM / RW) + mh * (BM / (2 * RW)) + m * 16 + lrow;
    // map block row -> {half section, row within half}
    int u = r / (BM / 2), rr = r % (BM / 2);
    return u * AH + rr * 128 + ((ks * 64 + lgrp * 16) ^ rsw);
  };
  auto boff = [&](int nf, int ks) {
    int r = wc * (BN / CW) + nf * 16 + lrow;
    return 2 * AH + r * 128 + ((ks * 64 + lgrp * 16) ^ rsw);
  };

  f32x4 acc[2 * MQ][NREP] = {};
  bf16x8 af[MQ][2], bf[NREP][2];

  const int nt = K / 64;
  // prologue
  stageA2(0, 0);
  stageB(0, 0);
  if constexpr (NBUF == 3) {
    stageA2(SB, 64);
    stageB(SB, 64);
  }

  int bcur = 0;
  for (int t = 0; t < nt; ++t) {
    const int cur = bcur * SB;
    const int nx1 = (bcur + 1 < NBUF ? bcur + 1 : bcur + 1 - NBUF) * SB;
    const int nx2 = (bcur + 2 < NBUF ? bcur + 2 : bcur + 2 - NBUF) * SB;
    const bool pf1 = (t + 1) < nt, pf2 = (t + 2) < nt;
    const char* base = Lds + cur;

    // ---- q0: counted wait + the ONE barrier per tile ----
    if constexpr (NBUF == 2) {
      if (pf1) {
        stageA2(nx1, (t + 1) * 64);
        if constexpr (La == 2) asm volatile("s_waitcnt vmcnt(4)" ::: "memory");
        else                   asm volatile("s_waitcnt vmcnt(2)" ::: "memory");
      } else {
        asm volatile("s_waitcnt vmcnt(0)" ::: "memory");
      }
    } else {  // NBUF == 3: drain stages(t) (2 tiles old), keep stages(t+1)
      if (pf1) asm volatile("s_waitcnt vmcnt(6)" ::: "memory");
      else     asm volatile("s_waitcnt vmcnt(0)" ::: "memory");
    }
    __builtin_amdgcn_sched_barrier(0);
    __builtin_amdgcn_s_barrier();
    __builtin_amdgcn_sched_barrier(0);
    if constexpr (NBUF == 3) {
      if (pf2) stageA2(nx2, (t + 2) * 64);  // after barrier: buf free of readers
    }
#pragma unroll
    for (int m = 0; m < MQ; ++m)
#pragma unroll
      for (int ks = 0; ks < 2; ++ks)
        af[m][ks] = *reinterpret_cast<const bf16x8*>(base + aoff(0, m, ks));
#pragma unroll
    for (int nf = 0; nf < NB0; ++nf)
#pragma unroll
      for (int ks = 0; ks < 2; ++ks)
        bf[nf][ks] = *reinterpret_cast<const bf16x8*>(base + boff(nf, ks));
    __builtin_amdgcn_s_setprio(1);
#pragma unroll
    for (int m = 0; m < MQ; ++m)
#pragma unroll
      for (int nf = 0; nf < NB0; ++nf)
#pragma unroll
        for (int ks = 0; ks < 2; ++ks)
          acc[m][nf] = __builtin_amdgcn_mfma_f32_16x16x32_bf16(af[m][ks], bf[nf][ks], acc[m][nf], 0, 0, 0);
    __builtin_amdgcn_s_setprio(0);

    // ---- q1: stage B ----
    if constexpr (NBUF == 2) { if (pf1) stageB(nx1, (t + 1) * 64); }
    else                     { if (pf2) stageB(nx2, (t + 2) * 64); }
#pragma unroll
    for (int nf = NB0; nf < NREP; ++nf)
#pragma unroll
      for (int ks = 0; ks < 2; ++ks)
        bf[nf][ks] = *reinterpret_cast<const bf16x8*>(base + boff(nf, ks));
    __builtin_amdgcn_s_setprio(1);
#pragma unroll
    for (int m = 0; m < MQ; ++m)
#pragma unroll
      for (int nf = NB0; nf < NREP; ++nf)
#pragma unroll
        for (int ks = 0; ks < 2; ++ks)
          acc[m][nf] = __builtin_amdgcn_mfma_f32_16x16x32_bf16(af[m][ks], bf[nf][ks], acc[m][nf], 0, 0, 0);
    __builtin_amdgcn_s_setprio(0);

    // ---- q2 ----
#pragma unroll
    for (int m = 0; m < MQ; ++m)
#pragma unroll
      for (int ks = 0; ks < 2; ++ks)
        af[m][ks] = *reinterpret_cast<const bf16x8*>(base + aoff(1, m, ks));
    __builtin_amdgcn_s_setprio(1);
#pragma unroll
    for (int m = 0; m < MQ; ++m)
#pragma unroll
      for (int nf = 0; nf < NB0; ++nf)
#pragma unroll
        for (int ks = 0; ks < 2; ++ks)
          acc[MQ + m][nf] = __builtin_amdgcn_mfma_f32_16x16x32_bf16(af[m][ks], bf[nf][ks], acc[MQ + m][nf], 0, 0, 0);
    __builtin_amdgcn_s_setprio(0);

    // ---- q3 ----
    __builtin_amdgcn_s_setprio(1);
#pragma unroll
    for (int m = 0; m < MQ; ++m)
#pragma unroll
      for (int nf = NB0; nf < NREP; ++nf)
#pragma unroll
        for (int ks = 0; ks < 2; ++ks)
          acc[MQ + m][nf] = __builtin_amdgcn_mfma_f32_16x16x32_bf16(af[m][ks], bf[nf][ks], acc[MQ + m][nf], 0, 0, 0);
    __builtin_amdgcn_s_setprio(0);

    bcur = (bcur + 1 < NBUF) ? bcur + 1 : 0;
  }

  // epilogue: bias + store
#pragma unroll
  for (int ni = 0; ni < NREP; ++ni) {
    int col = bn + wc * (BN / CW) + ni * 16 + lrow;
    float bv = bias[col];
#pragma unroll
    for (int mi = 0; mi < 2 * MQ; ++mi)
#pragma unroll
      for (int r = 0; r < 4; ++r) {
        int row = bm + wr * (BM / RW) + mi * 16 + lgrp * 4 + r;
        if constexpr (OBF)
          ((unsigned short*)Cp)[(size_t)row * N + col] = f32_bf16(acc[mi][ni][r] + bv);
        else
          ((float*)Cp)[(size_t)row * N + col] = acc[mi][ni][r] + bv;
      }
  }
}

// ---------------- RoPE + split (bf16 qkv input), vectorized ------------------
__global__ __launch_bounds__(256) void rope_split(const unsigned short* __restrict__ qkvb,
                                                  const float* __restrict__ ct,
                                                  const float* __restrict__ st,
                                                  unsigned short* __restrict__ Q,
                                                  unsigned short* __restrict__ Kh,
                                                  unsigned short* __restrict__ Vt) {
  int b = blockIdx.x;
  if (b < 5120) {
    int t = b * 256 + threadIdx.x;
    int d8 = (t & 15) * 8;
    int q = t >> 4;
    int s = q / 40;
    int slotg = q - s * 40;
    int g = slotg / 5, slot = slotg - g * 5;
    const unsigned short* base = qkvb + (size_t)s * QKV_OUT + g * 768 + slot * 128;
    bf16x8 x8 = *reinterpret_cast<const bf16x8*>(base + d8);
    bf16x8 r8 = *reinterpret_cast<const bf16x8*>(base + (d8 ^ 64));
    float4 c0 = *reinterpret_cast<const float4*>(ct + s * 64 + (d8 & 63));
    float4 c1 = *reinterpret_cast<const float4*>(ct + s * 64 + (d8 & 63) + 4);
    float4 s0 = *reinterpret_cast<const float4*>(st + s * 64 + (d8 & 63));
    float4 s1 = *reinterpret_cast<const float4*>(st + s * 64 + (d8 & 63) + 4);
    float cc[8] = {c0.x, c0.y, c0.z, c0.w, c1.x, c1.y, c1.z, c1.w};
    float ss[8] = {s0.x, s0.y, s0.z, s0.w, s1.x, s1.y, s1.z, s1.w};
    float sgn = (d8 < 64) ? -1.0f : 1.0f;
    float sc = (slot < 4) ? QSCALE : 1.0f;
    unsigned short o[8];
#pragma unroll
    for (int i = 0; i < 8; ++i) {
      float x = bf16_f32((unsigned short)x8[i]);
      float r = bf16_f32((unsigned short)r8[i]) * sgn;
      o[i] = f32_bf16((x * cc[i] + r * ss[i]) * sc);
    }
    unsigned short* dst = (slot < 4)
        ? Q + ((size_t)(g * 4 + slot) * SEQ + s) * HD + d8
        : Kh + ((size_t)g * SEQ + s) * HD + d8;
    *reinterpret_cast<uint4*>(dst) = *reinterpret_cast<uint4*>(o);
  } else {
    int t2 = (b - 5120) * 256 + threadIdx.x;
    int d = t2 & 127;
    int rest = t2 >> 7;
    int g = rest & 7;
    int s0 = (rest >> 3) * 8;
    const unsigned short* src = qkvb + (size_t)s0 * QKV_OUT + g * 768 + 640 + d;
    unsigned short o[8];
#pragma unroll
    for (int i = 0; i < 8; ++i) o[i] = src[(size_t)i * QKV_OUT];
    *reinterpret_cast<uint4*>(&Vt[((size_t)g * HD + d) * SEQ + s0]) =
        *reinterpret_cast<uint4*>(o);
  }
}

// next valid blocksparse j >= x for this qb (uniform across block), -1 if none.
__device__ inline int nextj(int x, int qb) {
  if (x > qb) return -1;
  if (qb - x < 16) return x;
  int v = (x & ~7) + 7;
  int w = qb - 15;
  return v < w ? v : w;
}

// ---------------- blocksparse flash attention (unchanged, R8-passing) --------
__global__ __launch_bounds__(256, 2) void attn32(const unsigned short* __restrict__ Q,
                                                 const unsigned short* __restrict__ Kh,
                                                 const unsigned short* __restrict__ Vt,
                                                 unsigned short* __restrict__ ctx) {
  const int g = blockIdx.x;
  const int y = (int)gridDim.y - 1 - (int)blockIdx.y;
  const int qb = y >> 1, half = y & 1;
  const int Q0 = y * 32;
  const int tid = threadIdx.x;
  const int wave = tid >> 6;
  const int h = g * 4 + wave;
  const int lane = tid & 63;
  const int l31 = lane & 31, hi = lane >> 5;

  __shared__ __align__(16) char Lds[65536];

  auto stage = [&](int bufb, int j) {
#pragma unroll
    for (int i = 0; i < 4; ++i) {
      int row = i * 16 + (tid >> 4);
      const unsigned short* src =
          Kh + ((size_t)(g * SEQ + j * 64 + row)) * HD + ((tid & 15) ^ (row & 15)) * 8;
      __builtin_amdgcn_global_load_lds(
          (const __attribute__((address_space(1))) unsigned int*)src,
          (__attribute__((address_space(3))) unsigned int*)(Lds + bufb + i * 4096 + (tid >> 6) * 1024),
          16, 0, 0);
    }
#pragma unroll
    for (int i = 0; i < 4; ++i) {
      int row = i * 32 + (tid >> 3);
      const unsigned short* src =
          Vt + ((size_t)(g * HD + row)) * SEQ + j * 64 + ((tid & 7) ^ (row & 7)) * 8;
      __builtin_amdgcn_global_load_lds(
          (const __attribute__((address_space(1))) unsigned int*)src,
          (__attribute__((address_space(3))) unsigned int*)(Lds + bufb + 16384 + i * 4096 + (tid >> 6) * 1024),
          16, 0, 0);
    }
  };

  bf16x8 qf[8];
  const unsigned short* qbase = Q + ((size_t)h * SEQ + Q0 + l31) * HD;
#pragma unroll
  for (int kk = 0; kk < 8; ++kk)
    qf[kk] = *reinterpret_cast<const bf16x8*>(qbase + kk * 16 + hi * 8);

  f32x16 ot[4] = {};
  float mrow = -1e30f, lsum = 0.f;

  const int kswz = l31 & 15;
  const int vswz = l31 & 7;

  int j = nextj(0, qb);
  int cur = 0;
  stage(0, j);
  asm volatile("s_waitcnt vmcnt(0)" ::: "memory");
  __builtin_amdgcn_sched_barrier(0);
  __builtin_amdgcn_s_barrier();
  __builtin_amdgcn_sched_barrier(0);

  while (true) {
    const int jn = (j < qb) ? nextj(j + 1, qb) : -1;
    if (jn >= 0) stage(cur ^ 32768, jn);

    const char* kb = Lds + cur;
    const char* vb = Lds + cur + 16384;
    const bool diag = (j == qb);
    const bool short_blk = diag && (half == 0);

    f32x16 st[2] = {};
    __builtin_amdgcn_s_setprio(1);
#pragma unroll
    for (int kk = 0; kk < 8; ++kk) {
      bf16x8 k0 = *reinterpret_cast<const bf16x8*>(
          kb + (size_t)l31 * 256 + (((2 * kk + hi) ^ kswz) * 16));
      st[0] = __builtin_amdgcn_mfma_f32_32x32x16_bf16(k0, qf[kk], st[0], 0, 0, 0);
      if (!short_blk) {
        bf16x8 k1 = *reinterpret_cast<const bf16x8*>(
            kb + (size_t)(32 + l31) * 256 + (((2 * kk + hi) ^ kswz) * 16));
        st[1] = __builtin_amdgcn_mfma_f32_32x32x16_bf16(k1, qf[kk], st[1], 0, 0, 0);
      }
    }
    __builtin_amdgcn_s_setprio(0);

    if (diag) {
      int qrel = half * 32 + l31;
#pragma unroll
      for (int kt = 0; kt < 2; ++kt)
#pragma unroll
        for (int r = 0; r < 16; ++r) {
          int krel = kt * 32 + (r & 3) + 8 * (r >> 2) + 4 * hi;
          if (krel > qrel) st[kt][r] = -1e30f;
        }
    }

    float t16[16];
#pragma unroll
    for (int r = 0; r < 16; ++r) t16[r] = fmaxf(st[0][r], st[1][r]);
#pragma unroll
    for (int sft = 8; sft >= 1; sft >>= 1)
#pragma unroll
      for (int r = 0; r < sft; ++r) t16[r] = fmaxf(t16[r], t16[r + sft]);
    float vm = xmax32(t16[0]);

    if (!__all(vm - mrow <= 8.0f)) {
      float nm = fmaxf(mrow, vm);
      float corr = __builtin_amdgcn_exp2f(mrow - nm);
      lsum *= corr;
#pragma unroll
      for (int dt = 0; dt < 4; ++dt)
#pragma unroll
        for (int r = 0; r < 16; ++r) ot[dt][r] *= corr;
      mrow = nm;
    }

    float s4[4] = {0.f, 0.f, 0.f, 0.f};
#pragma unroll
    for (int kt = 0; kt < 2; ++kt)
#pragma unroll
      for (int r = 0; r < 16; ++r) {
        float p = __builtin_amdgcn_exp2f(st[kt][r] - mrow);
        st[kt][r] = p;
        s4[r & 3] += p;
      }
    lsum += xadd32((s4[0] + s4[1]) + (s4[2] + s4[3]));

    bf16x8 pb[4];
#pragma unroll
    for (int s = 0; s < 4; ++s) {
      int kt = s >> 1, g0 = (s & 1) * 2, g1 = g0 + 1;
      unsigned int a0 = pk(st[kt][4 * g0 + 0], st[kt][4 * g0 + 1]);
      unsigned int a1 = pk(st[kt][4 * g0 + 2], st[kt][4 * g0 + 3]);
      unsigned int b0 = pk(st[kt][4 * g1 + 0], st[kt][4 * g1 + 1]);
      unsigned int b1 = pk(st[kt][4 * g1 + 2], st[kt][4 * g1 + 3]);
      pswap(a0, b0);
      pswap(a1, b1);
      union { unsigned int u[4]; bf16x8 v; } t;
      t.u[0] = a0; t.u[1] = a1; t.u[2] = b0; t.u[3] = b1;
      pb[s] = t.v;
    }

    const int smax = short_blk ? 2 : 4;
    __builtin_amdgcn_s_setprio(1);
#pragma unroll
    for (int dt = 0; dt < 4; ++dt) {
      const char* vrow = vb + (size_t)(dt * 32 + l31) * 128;
#pragma unroll
      for (int s = 0; s < 4; ++s)
        if (s < smax)
          ot[dt] = __builtin_amdgcn_mfma_f32_32x32x16_bf16(
              *reinterpret_cast<const bf16x8*>(vrow + (((2 * s + hi) ^ vswz) * 16)),
              pb[s], ot[dt], 0, 0, 0);
    }
    __builtin_amdgcn_s_setprio(0);

    if (jn < 0) break;
    asm volatile("s_waitcnt vmcnt(0)" ::: "memory");
    __builtin_amdgcn_sched_barrier(0);
    __builtin_amdgcn_s_barrier();
    __builtin_amdgcn_sched_barrier(0);
    j = jn;
    cur ^= 32768;
  }

  __syncthreads();
  char* W = Lds + wave * 8192;
  float inv = 1.0f / lsum;
  const int swz = (l31 & 7) << 4;
#pragma unroll
  for (int dt = 0; dt < 4; ++dt)
#pragma unroll
    for (int gg = 0; gg < 4; ++gg) {
      unsigned int u0 = pk(ot[dt][4 * gg + 0] * inv, ot[dt][4 * gg + 1] * inv);
      unsigned int u1 = pk(ot[dt][4 * gg + 2] * inv, ot[dt][4 * gg + 3] * inv);
      int off = (dt * 64 + gg * 16 + hi * 8) ^ swz;
      *reinterpret_cast<uint2*>(W + l31 * 256 + off) = make_uint2(u0, u1);
    }
#pragma unroll
  for (int i = 0; i < 8; ++i) {
    int row = lane >> 1;
    int t = (lane & 1) * 8 + i;
    bf16x8 vv = *reinterpret_cast<const bf16x8*>(
        W + row * 256 + ((t * 16) ^ ((row & 7) << 4)));
    *reinterpret_cast<bf16x8*>(&ctx[(size_t)(Q0 + row) * HIDDEN + h * HD + t * 8]) = vv;
  }
}

extern "C" void kernel_launch(void* const* d_in, const int* in_sizes, int n_in,
                              void* d_out, int out_size, void* d_ws, size_t ws_size,
                              hipStream_t stream) {
  const float* hidden  = (const float*)d_in[0];
  const float* w_qkv   = (const float*)d_in[1];
  const float* b_qkv   = (const float*)d_in[2];
  const float* w_dense = (const float*)d_in[3];
  const float* b_dense = (const float*)d_in[4];
  float* out = (float*)d_out;

  char* p = (char*)d_ws;
  unsigned short* hid_bf  = (unsigned short*)p; p += (size_t)SEQ * HIDDEN * 2;
  unsigned short* wqkv_bf = (unsigned short*)p; p += (size_t)QKV_OUT * HIDDEN * 2;
  unsigned short* wd_bf   = (unsigned short*)p; p += (size_t)HIDDEN * HIDDEN * 2;
  unsigned short* qkvb    = (unsigned short*)p; p += (size_t)SEQ * QKV_OUT * 2;
  unsigned short* Qb      = (unsigned short*)p; p += (size_t)NH * SEQ * HD * 2;
  unsigned short* Kb      = (unsigned short*)p; p += (size_t)NKV * SEQ * HD * 2;
  unsigned short* Vt      = (unsigned short*)p; p += (size_t)NKV * HD * SEQ * 2;
  float* ct               = (float*)p;          p += (size_t)SEQ * 64 * 4;
  float* st               = (float*)p;          p += (size_t)SEQ * 64 * 4;
  unsigned short* ctx = hid_bf;  // hidden_bf16 dead after QKV GEMM

  const int prep_blocks = (int)((N1 + N2 + N4 + N3 + 255) / 256);
  prep<<<prep_blocks, 256, 0, stream>>>(hidden, hid_bf, w_qkv, wqkv_bf,
                                        w_dense, wd_bf, ct, st);

  // QKV: BM=256 x BN=192, wave grid 4x2 (lower LDS redundancy), 2 buffers.
  gemmG<256, 192, 4, 2, 4, 8, true>
      <<<dim3((SEQ / 256) * (QKV_OUT / 192)), 512, 0, stream>>>(
          hid_bf, wqkv_bf, b_qkv, qkvb, SEQ, QKV_OUT, HIDDEN);
  rope_split<<<5120 + 1024, 256, 0, stream>>>(qkvb, ct, st, Qb, Kb, Vt);
  attn32<<<dim3(NKV, SEQ / 32), 256, 0, stream>>>(Qb, Kb, Vt, ctx);
  // dense: BM=128 x BN=256, wave grid 2x4 (R17-identical indexing), 3 buffers
  // (deeper prefetch: drained loads are 2 full tiles old).
  gemmG<128, 256, 2, 3, 8, 4, false>
      <<<dim3((SEQ / 128) * (HIDDEN / 256)), 512, 0, stream>>>(
          ctx, wd_bf, b_dense, out, SEQ, HIDDEN, HIDDEN);
}